// Round 14
// baseline (898.979 us; speedup 1.0000x reference)
//
#include <hip/hip_runtime.h>
#include <hip/hip_bf16.h>

#define N_NODES  100000
#define N_EDGES  300000
#define FEAT     256
#define N_GRAPHS 500
#define N_LAYERS 6
#define SCAN_B   1024

typedef __attribute__((ext_vector_type(8))) short v8s;   // 8 x bf16 bits (4 VGPRs)
typedef __attribute__((ext_vector_type(4))) float v4f;   // MFMA accumulator

__device__ __forceinline__ unsigned short f2bf(float f) {
    unsigned u = __float_as_uint(f);
    unsigned r = u + 0x7fffu + ((u >> 16) & 1u);   // RNE
    return (unsigned short)(r >> 16);
}
__device__ __forceinline__ float bf2f(unsigned short b) {
    return __uint_as_float(((unsigned)b) << 16);
}

__device__ __forceinline__ void gload16(const ushort* g, ushort* l) {
    __builtin_amdgcn_global_load_lds((const __attribute__((address_space(1))) void*)g,
                                     (__attribute__((address_space(3))) void*)l,
                                     16, 0, 0);
}
__device__ __forceinline__ void gload4(const ushort* g, ushort* l) {
    __builtin_amdgcn_global_load_lds((const __attribute__((address_space(1))) void*)g,
                                     (__attribute__((address_space(3))) void*)l,
                                     4, 0, 0);
}

// ---- init: x (f32) -> xb (bf16) ----
__global__ __launch_bounds__(256) void init_kernel(const float* __restrict__ x,
                                                   ushort* __restrict__ xb) {
    int i = blockIdx.x * 256 + threadIdx.x;           // per 4 elements
    if ((size_t)i * 4 >= (size_t)N_NODES * FEAT) return;
    float4 v = ((const float4*)x)[i];
    ((ushort4*)xb)[i] = make_ushort4(f2bf(v.x), f2bf(v.y), f2bf(v.z), f2bf(v.w));
}

// ---- weights f32 -> bf16, all layers at once ----
__global__ __launch_bounds__(256) void wconv_kernel(const float* __restrict__ Wl,
                                                    const float* __restrict__ Wr,
                                                    ushort* __restrict__ wlb,
                                                    ushort* __restrict__ wrb) {
    int i = blockIdx.x * 256 + threadIdx.x;           // per 4 elements
    if ((size_t)i * 4 >= (size_t)N_LAYERS * FEAT * FEAT) return;
    float4 a = ((const float4*)Wl)[i];
    float4 b = ((const float4*)Wr)[i];
    ((ushort4*)wlb)[i] = make_ushort4(f2bf(a.x), f2bf(a.y), f2bf(a.z), f2bf(a.w));
    ((ushort4*)wrb)[i] = make_ushort4(f2bf(b.x), f2bf(b.y), f2bf(b.z), f2bf(b.w));
}

// ================= CSR construction (counting sort by dst) =================

__global__ __launch_bounds__(256) void hist_kernel(const int* __restrict__ dst,
                                                   unsigned* __restrict__ degu) {
    int e = blockIdx.x * 256 + threadIdx.x;
    if (e < N_EDGES) atomicAdd(&degu[dst[e]], 1u);
}

__global__ __launch_bounds__(SCAN_B) void scan_blocks(const unsigned* __restrict__ degu,
                                                      unsigned* __restrict__ excl,
                                                      unsigned* __restrict__ bsum) {
    __shared__ unsigned tmp[SCAN_B];
    int i = blockIdx.x * SCAN_B + threadIdx.x;
    unsigned v = (i < N_NODES) ? degu[i] : 0u;
    tmp[threadIdx.x] = v;
    __syncthreads();
    for (int off = 1; off < SCAN_B; off <<= 1) {
        unsigned add = (threadIdx.x >= off) ? tmp[threadIdx.x - off] : 0u;
        __syncthreads();
        tmp[threadIdx.x] += add;
        __syncthreads();
    }
    if (i < N_NODES) excl[i] = tmp[threadIdx.x] - v;
    if (threadIdx.x == SCAN_B - 1) bsum[blockIdx.x] = tmp[SCAN_B - 1];
}

__global__ void scan_tops(unsigned* __restrict__ bsum, int nb) {
    unsigned run = 0;
    for (int b = 0; b < nb; ++b) { unsigned t = bsum[b]; bsum[b] = run; run += t; }
}

__global__ __launch_bounds__(256) void finalize_rowptr(const unsigned* __restrict__ excl,
                                                       const unsigned* __restrict__ bsum,
                                                       unsigned* __restrict__ rowptr,
                                                       unsigned* __restrict__ cursor) {
    int i = blockIdx.x * 256 + threadIdx.x;
    if (i < N_NODES) {
        unsigned v = excl[i] + bsum[i / SCAN_B];
        rowptr[i] = v;
        cursor[i] = v;
    }
    if (i == N_NODES) rowptr[N_NODES] = N_EDGES;
}

__global__ __launch_bounds__(256) void scatter_kernel(const int* __restrict__ ei,
                                                      unsigned* __restrict__ cursor,
                                                      unsigned* __restrict__ col) {
    int e = blockIdx.x * 256 + threadIdx.x;
    if (e >= N_EDGES) return;
    int d = ei[N_EDGES + e];
    unsigned p = atomicAdd(&cursor[d], 1u);
    col[p] = (unsigned)ei[e];
}

// ---- per-graph [start,end) bounds from sorted batch: boundary detection ----
__global__ __launch_bounds__(256) void bounds_kernel(const int* __restrict__ batch,
                                                     unsigned* __restrict__ gs,
                                                     unsigned* __restrict__ ge) {
    int i = blockIdx.x * 256 + threadIdx.x;
    if (i >= N_NODES) return;
    int g = batch[i];
    int gp = (i == 0) ? -1 : batch[i - 1];
    if (g != gp) gs[g] = (unsigned)i;
    int gn = (i == N_NODES - 1) ? -1 : batch[i + 1];
    if (g != gn) ge[g] = (unsigned)(i + 1);
}

// ============================================================================
// Fused layer v5: x@Wr phases FIRST with the CSR mean-gather interleaved
// between them (T14 issue-early / consume-late), then mean@Wl phases from Ms.
//   xbn = bf16( relu([mean|x] @ [Wl|Wr]^T + bl) + x )
// BM=64, BN=256, BK=32, 8 waves (1x8 col stripes), grid 1563.
// vmcnt ledger (per wave, all counts static):
//   stage = 4 VMEM (B 2x16B + X 2x4B, uniform across waves)
//   steady queue entering phase top: [stage(cur)x4, gather-slot x4]
//   phase top: vmcnt(4) -> stage done; consume after MFMA: vmcnt(4)
//   masked gather loads are unconditional (clamped, junk -> hot row 0)
// ============================================================================
#define CPAD  264    // epilogue row stride (256 + 8)

__global__ __launch_bounds__(512, 4) void gemm_kernel(
        const unsigned* __restrict__ rowptr,
        const unsigned* __restrict__ col,
        const ushort* __restrict__ xb,    // cur x (row-major bf16)
        const ushort* __restrict__ B0,    // Wl slice [256][256]
        const ushort* __restrict__ B1,    // Wr slice
        const float*  __restrict__ bias,  // bl slice [256]
        ushort* __restrict__ xbn) {       // next-layer x
    __shared__ ushort lds[36864];         // 72 KB
    ushort* Ms  = lds;                    // 16384 ushorts (32 KB)
    ushort* Bs0 = lds + 16384;
    ushort* Bs1 = lds + 24576;
    ushort* Xs0 = lds + 32768;
    ushort* Xs1 = lds + 34816;
    ushort* Cs  = lds;                    // epilogue reuse [64][CPAD]

    const int tid  = threadIdx.x;
    const int lane = tid & 63;
    const int wid  = tid >> 6;            // 0..7 (col stripe)
    const int row0 = blockIdx.x * 64;
    const int h    = lane >> 5;           // half-wave
    const int l32  = lane & 31;

    // ---- B staging addresses (16B chunks, as R13) ----
    const int pB0  = tid >> 3;
    const int w0B0 = ((tid & 7) ^ (pB0 & 7)) << 4;
    const int rB0  = 2 * pB0 + (w0B0 >> 6);
    const int cbB0 = w0B0 & 63;
    const int c1   = tid + 512;
    const int pB1  = c1 >> 3;
    const int w0B1 = ((c1 & 7) ^ (pB1 & 7)) << 4;
    const int rB1  = 2 * pB1 + (w0B1 >> 6);
    const int cbB1 = w0B1 & 63;
    // ---- X staging addresses (4B chunks, 2 per thread, wave-uniform bases) ----
    int xrow_[2], xcb_[2];
    #pragma unroll
    for (int q = 0; q < 2; ++q) {
        int L    = (wid * 2 + q) * 256 + (lane << 2);   // LDS byte
        int line = L >> 7;
        int wl   = (L & 127) ^ ((line & 7) << 4);
        int row  = 2 * line + (wl >> 6);
        int grow = row0 + row;
        xrow_[q] = grow < N_NODES ? grow : N_NODES - 1;
        xcb_[q]  = wl & 63;
    }

    #define STAGE_B(bufPtr, kt) do {                                              \
        const ushort* Bsrc = ((kt) < 8) ? B0 : B1;                                \
        const int kb = ((kt) & 7) * 32;                                           \
        gload16(Bsrc + (size_t)rB0 * FEAT + kb + (cbB0 >> 1), (bufPtr) + tid * 8);\
        gload16(Bsrc + (size_t)rB1 * FEAT + kb + (cbB1 >> 1), (bufPtr) + (size_t)c1 * 8); \
    } while (0)

    #define STAGE_X4(bufPtr, kt) do {                                             \
        const int kb = ((kt) & 7) * 32;                                           \
        gload4(xb + (size_t)xrow_[0] * FEAT + kb + (xcb_[0] >> 1), (bufPtr) + (wid * 2 + 0) * 128); \
        gload4(xb + (size_t)xrow_[1] * FEAT + kb + (xcb_[1] >> 1), (bufPtr) + (wid * 2 + 1) * 128); \
    } while (0)

    // ================= prologue =================
    STAGE_B(Bs0, 8);                      // exec-phase 0 = kt 8 (x @ Wr)
    STAGE_X4(Xs0, 8);

    // gather row state (rows nl = wid*8 + p*2 + h, p = 0..3)
    unsigned s_[4], e_[4];
    #pragma unroll
    for (int p = 0; p < 4; ++p) {
        int node = row0 + wid * 8 + p * 2 + h;
        bool ok  = node < N_NODES;
        int  cn  = ok ? node : (N_NODES - 1);
        unsigned sv = rowptr[cn];
        unsigned ev = rowptr[cn + 1];
        s_[p] = ok ? sv : 0u;
        e_[p] = ok ? ev : 0u;
    }
    asm volatile("s_waitcnt vmcnt(0)" ::: "memory");   // stage(ph0) + rowptr drained
    int cvv[4];
    #pragma unroll
    for (int p = 0; p < 4; ++p) {
        unsigned idx = s_[p] + (unsigned)l32;
        idx = idx < (unsigned)(N_EDGES - 1) ? idx : (unsigned)(N_EDGES - 1);
        cvv[p] = (int)col[idx];
    }

    float a0=0.f,a1=0.f,a2=0.f,a3=0.f,a4=0.f,a5=0.f,a6=0.f,a7=0.f;
    v8s g0, g1, g2, g3;

    #define GISSUE(p, jb) do {                                                    \
        int dg_ = (int)(e_[p] - s_[p]);                                           \
        unsigned q0_ = (unsigned)__shfl(cvv[p], (h << 5) + (jb) + 0);             \
        unsigned q1_ = (unsigned)__shfl(cvv[p], (h << 5) + (jb) + 1);             \
        unsigned q2_ = (unsigned)__shfl(cvv[p], (h << 5) + (jb) + 2);             \
        unsigned q3_ = (unsigned)__shfl(cvv[p], (h << 5) + (jb) + 3);             \
        q0_ = ((jb) + 0 < dg_) ? q0_ : 0u;                                        \
        q1_ = ((jb) + 1 < dg_) ? q1_ : 0u;                                        \
        q2_ = ((jb) + 2 < dg_) ? q2_ : 0u;                                        \
        q3_ = ((jb) + 3 < dg_) ? q3_ : 0u;                                        \
        g0 = *(const v8s*)(xb + (size_t)q0_ * FEAT + l32 * 8);                    \
        g1 = *(const v8s*)(xb + (size_t)q1_ * FEAT + l32 * 8);                    \
        g2 = *(const v8s*)(xb + (size_t)q2_ * FEAT + l32 * 8);                    \
        g3 = *(const v8s*)(xb + (size_t)q3_ * FEAT + l32 * 8);                    \
    } while (0)

    #define GCONSUME(p, jb) do {                                                  \
        int dg_ = (int)(e_[p] - s_[p]);                                           \
        float m0_ = ((jb) + 0 < dg_) ? 1.f : 0.f;                                 \
        float m1_ = ((jb) + 1 < dg_) ? 1.f : 0.f;                                 \
        float m2_ = ((jb) + 2 < dg_) ? 1.f : 0.f;                                 \
        float m3_ = ((jb) + 3 < dg_) ? 1.f : 0.f;                                 \
        a0 += m0_*bf2f((ushort)g0[0]) + m1_*bf2f((ushort)g1[0]) + m2_*bf2f((ushort)g2[0]) + m3_*bf2f((ushort)g3[0]); \
        a1 += m0_*bf2f((ushort)g0[1]) + m1_*bf2f((ushort)g1[1]) + m2_*bf2f((ushort)g2[1]) + m3_*bf2f((ushort)g3[1]); \
        a2 += m0_*bf2f((ushort)g0[2]) + m1_*bf2f((ushort)g1[2]) + m2_*bf2f((ushort)g2[2]) + m3_*bf2f((ushort)g3[2]); \
        a3 += m0_*bf2f((ushort)g0[3]) + m1_*bf2f((ushort)g1[3]) + m2_*bf2f((ushort)g2[3]) + m3_*bf2f((ushort)g3[3]); \
        a4 += m0_*bf2f((ushort)g0[4]) + m1_*bf2f((ushort)g1[4]) + m2_*bf2f((ushort)g2[4]) + m3_*bf2f((ushort)g3[4]); \
        a5 += m0_*bf2f((ushort)g0[5]) + m1_*bf2f((ushort)g1[5]) + m2_*bf2f((ushort)g2[5]) + m3_*bf2f((ushort)g3[5]); \
        a6 += m0_*bf2f((ushort)g0[6]) + m1_*bf2f((ushort)g1[6]) + m2_*bf2f((ushort)g2[6]) + m3_*bf2f((ushort)g3[6]); \
        a7 += m0_*bf2f((ushort)g0[7]) + m1_*bf2f((ushort)g1[7]) + m2_*bf2f((ushort)g2[7]) + m3_*bf2f((ushort)g3[7]); \
    } while (0)

    #define GFINAL(p) do {                                                        \
        int dg_ = (int)(e_[p] - s_[p]);                                           \
        if (dg_ > 8) {                    /* rare (~1%): serial remainder */      \
            for (int j = 8; j < dg_; ++j) {                                       \
                unsigned si_;                                                     \
                if (j < 32) si_ = (unsigned)__shfl(cvv[p], (h << 5) + j);         \
                else        si_ = col[s_[p] + (unsigned)j];                       \
                v8s v_ = *(const v8s*)(xb + (size_t)si_ * FEAT + l32 * 8);        \
                a0 += bf2f((ushort)v_[0]); a1 += bf2f((ushort)v_[1]);             \
                a2 += bf2f((ushort)v_[2]); a3 += bf2f((ushort)v_[3]);             \
                a4 += bf2f((ushort)v_[4]); a5 += bf2f((ushort)v_[5]);             \
                a6 += bf2f((ushort)v_[6]); a7 += bf2f((ushort)v_[7]);             \
            }                                                                      \
        }                                                                          \
        float r_ = 1.0f / fmaxf((float)dg_, 1.0f);                                \
        v8s o_;                                                                    \
        o_[0]=(short)f2bf(a0*r_); o_[1]=(short)f2bf(a1*r_);                       \
        o_[2]=(short)f2bf(a2*r_); o_[3]=(short)f2bf(a3*r_);                       \
        o_[4]=(short)f2bf(a4*r_); o_[5]=(short)f2bf(a5*r_);                       \
        o_[6]=(short)f2bf(a6*r_); o_[7]=(short)f2bf(a7*r_);                       \
        int nl_ = wid * 8 + (p) * 2 + h;                                          \
        *(v8s*)((char*)Ms + nl_ * 512 + ((l32 * 16) ^ ((nl_ & 7) << 4))) = o_;    \
        a0=0.f;a1=0.f;a2=0.f;a3=0.f;a4=0.f;a5=0.f;a6=0.f;a7=0.f;                  \
    } while (0)

    GISSUE(0, 0);                          // slot 0 in flight before phase 0

    // ======================= K-loop =======================
    v4f acc[4][2] = {};
    const int fr  = lane & 15;
    const int cbk = (lane >> 4) << 4;

    #define FRAG(basePtr, row) \
        (*(const v8s*)((const char*)(basePtr) + (((row) >> 1) * 128 + \
            ((((row) & 1) << 6) + cbk) ^ ((((row) >> 1) & 7) << 4))))

    #define AFRAG_M(kt, row) \
        (*(const v8s*)((const char*)Ms + (row) * 512 + \
            ((((kt) << 6) + cbk) ^ (((row) & 7) << 4))))

    #define MFMA8() do {                                                          \
        _Pragma("unroll")                                                         \
        for (int i = 0; i < 4; ++i)                                               \
            _Pragma("unroll")                                                     \
            for (int j = 0; j < 2; ++j)                                           \
                acc[i][j] = __builtin_amdgcn_mfma_f32_16x16x32_bf16(a[i], b[j], acc[i][j], 0, 0, 0); \
    } while (0)

    // ---- x @ Wr phases (exec-ph 0..7 = kt 8..15) with gather slots ----
    #pragma unroll
    for (int ph = 0; ph < 8; ++ph) {
        if (ph > 0) asm volatile("s_waitcnt vmcnt(4)" ::: "memory");  // stage(ph) done
        __builtin_amdgcn_s_barrier();
        if (ph < 7) {
            STAGE_B((ph & 1) ? Bs0 : Bs1, 9 + ph);
            STAGE_X4((ph & 1) ? Xs0 : Xs1, 9 + ph);
        } else {
            STAGE_B(Bs0, 0);               // exec-ph 8 = kt 0 (mean phases, B only)
        }
        v8s a[4], b[2];
        {
            const ushort* xp = (ph & 1) ? Xs1 : Xs0;
            #pragma unroll
            for (int i = 0; i < 4; ++i) a[i] = FRAG(xp, i * 16 + fr);
            const ushort* bp = (ph & 1) ? Bs1 : Bs0;
            #pragma unroll
            for (int j = 0; j < 2; ++j) b[j] = FRAG(bp, wid * 32 + j * 16 + fr);
        }
        asm volatile("s_waitcnt lgkmcnt(0)" ::: "memory");
        __builtin_amdgcn_sched_barrier(0);
        __builtin_amdgcn_s_setprio(1);
        MFMA8();
        __builtin_amdgcn_s_setprio(0);
        // ---- gather slot ph ----
        const int p = ph >> 1;
        if ((ph & 1) == 0) {
            asm volatile("s_waitcnt vmcnt(4)" ::: "memory");   // slot loads done
            if (p == 0) GCONSUME(0, 0); else if (p == 1) GCONSUME(1, 0);
            else if (p == 2) GCONSUME(2, 0); else GCONSUME(3, 0);
            if (p == 0) GISSUE(0, 4); else if (p == 1) GISSUE(1, 4);
            else if (p == 2) GISSUE(2, 4); else GISSUE(3, 4);
        } else {
            if (ph == 7) asm volatile("s_waitcnt vmcnt(2)" ::: "memory");
            else         asm volatile("s_waitcnt vmcnt(4)" ::: "memory");
            if (p == 0) { GCONSUME(0, 4); GFINAL(0); GISSUE(1, 0); }
            else if (p == 1) { GCONSUME(1, 4); GFINAL(1); GISSUE(2, 0); }
            else if (p == 2) { GCONSUME(2, 4); GFINAL(2); GISSUE(3, 0); }
            else { GCONSUME(3, 4); GFINAL(3); }
        }
    }

    // ---- mean @ Wl phases (exec-ph 8..15 = kt 0..7), A from Ms ----
    #pragma unroll
    for (int ph = 8; ph < 16; ++ph) {
        const int kt = ph - 8;
        if (ph == 8) asm volatile("s_waitcnt lgkmcnt(0)" ::: "memory"); // own Ms writes
        asm volatile("s_waitcnt vmcnt(0)" ::: "memory");                // stage(ph) done
        __builtin_amdgcn_s_barrier();
        if (kt < 7) STAGE_B((ph & 1) ? Bs0 : Bs1, kt + 1);
        v8s a[4], b[2];
        #pragma unroll
        for (int i = 0; i < 4; ++i) a[i] = AFRAG_M(kt, i * 16 + fr);
        {
            const ushort* bp = (ph & 1) ? Bs1 : Bs0;
            #pragma unroll
            for (int j = 0; j < 2; ++j) b[j] = FRAG(bp, wid * 32 + j * 16 + fr);
        }
        asm volatile("s_waitcnt lgkmcnt(0)" ::: "memory");
        __builtin_amdgcn_sched_barrier(0);
        __builtin_amdgcn_s_setprio(1);
        MFMA8();
        __builtin_amdgcn_s_setprio(0);
    }

    // ================= epilogue (coalesced via LDS) =================
    __builtin_amdgcn_s_barrier();   // all waves past final Ms/Bs reads
    {
        const int orow = (lane >> 4) * 4;
        const int ocol = lane & 15;
        #pragma unroll
        for (int j = 0; j < 2; ++j) {
            int colg = wid * 32 + j * 16 + ocol;
            float bv = bias[colg];
            #pragma unroll
            for (int i = 0; i < 4; ++i) {
                int rl = i * 16 + orow;
                #pragma unroll
                for (int r = 0; r < 4; ++r)
                    Cs[(rl + r) * CPAD + colg] = f2bf(fmaxf(acc[i][j][r] + bv, 0.0f));
            }
        }
    }
    __syncthreads();
    {
        int rl  = tid >> 3;                  // 0..63
        int row = row0 + rl;
        #pragma unroll
        for (int it = 0; it < 4; ++it) {
            int c0 = (tid & 7) * 8 + it * 64;
            v8s y = *(const v8s*)(Cs + rl * CPAD + c0);
            if (row < N_NODES) {
                v8s xv = *(const v8s*)(xb + (size_t)row * FEAT + c0);
                v8s o;
                #pragma unroll
                for (int k = 0; k < 8; ++k)
                    o[k] = (short)f2bf(bf2f((ushort)y[k]) + bf2f((ushort)xv[k]));
                *(v8s*)(xbn + (size_t)row * FEAT + c0) = o;
            }
        }
    }
    #undef STAGE_B
    #undef STAGE_X4
    #undef GISSUE
    #undef GCONSUME
    #undef GFINAL
    #undef FRAG
    #undef AFRAG_M
    #undef MFMA8
}

// ============================================================================
// Parallel segment softmax (R10): 1 block (512 thr) per graph.
// ============================================================================
__global__ __launch_bounds__(512) void smax_kernel(const ushort* __restrict__ xb,
                                                   const unsigned* __restrict__ gs,
                                                   const unsigned* __restrict__ ge,
                                                   const float* __restrict__ t,
                                                   float* __restrict__ out) {
    __shared__ float sm[16 * 256];
    __shared__ float sd[16 * 256];
    __shared__ float sa[16 * 256];
    const int g   = blockIdx.x;
    const unsigned s = gs[g], e = ge[g];
    const float tv2 = t[0] * 1.44269504f;   // log2(e) * t
    const int tid = threadIdx.x;
    const int c   = tid >> 5;               // chunk 0..15
    const int f8  = (tid & 31) * 8;         // feature base

    float m[8], den[8], acc[8];
    #pragma unroll
    for (int k = 0; k < 8; ++k) { m[k] = -INFINITY; den[k] = 0.f; acc[k] = 0.f; }

    if (s < e) {
        for (unsigned n = s + c; n < e; n += 16) {
            v8s v = *(const v8s*)(xb + (size_t)n * FEAT + f8);
            #pragma unroll
            for (int k = 0; k < 8; ++k) {
                float xv = bf2f((ushort)v[k]);
                float s2 = xv * tv2;                 // t*x in log2 domain
                float mn = fmaxf(m[k], s2);
                float sc = exp2f(m[k] - mn);         // 0 on first iter
                float w  = exp2f(s2 - mn);
                den[k] = den[k] * sc + w;
                acc[k] = acc[k] * sc + w * xv;
                m[k] = mn;
            }
        }
    }
    #pragma unroll
    for (int k = 0; k < 8; ++k) {
        sm[c * 256 + f8 + k] = m[k];
        sd[c * 256 + f8 + k] = den[k];
        sa[c * 256 + f8 + k] = acc[k];
    }
    __syncthreads();
    if (tid < 256) {
        if (s < e) {
            const int f = tid;
            float M = -INFINITY;
            #pragma unroll
            for (int cc = 0; cc < 16; ++cc) M = fmaxf(M, sm[cc * 256 + f]);
            float D = 0.f, A = 0.f;
            #pragma unroll
            for (int cc = 0; cc < 16; ++cc) {
                float w = exp2f(sm[cc * 256 + f] - M);   // 0 for empty chunks
                D += sd[cc * 256 + f] * w;
                A += sa[cc * 256 + f] * w;
            }
            out[(size_t)g * FEAT + tid] = A / fmaxf(D, 1e-16f);
        } else {
            out[(size_t)g * FEAT + tid] = 0.f;   // empty segment -> 0 per reference
        }
    }
}

extern "C" void kernel_launch(void* const* d_in, const int* in_sizes, int n_in,
                              void* d_out, int out_size, void* d_ws, size_t ws_size,
                              hipStream_t stream) {
    const float* x     = (const float*)d_in[0];
    const int*   ei    = (const int*)d_in[1];    // [2, E]: row0=src, row1=dst
    const int*   batch = (const int*)d_in[2];
    const float* Wl    = (const float*)d_in[3];  // [L, F, F]
    const float* bl    = (const float*)d_in[4];  // [L, F]
    const float* Wr    = (const float*)d_in[5];  // [L, F, F]
    const float* t     = (const float*)d_in[6];  // [1]
    float* out = (float*)d_out;

    const size_t NF2 = (size_t)N_NODES * FEAT * 2;   // 51,200,000
    const size_t WSZ = (size_t)N_LAYERS * FEAT * FEAT * 2;

    char* ws = (char*)d_ws;
    size_t off = 0;
    ushort* xb0   = (ushort*)(ws + off); off += NF2;
    ushort* xb1   = (ushort*)(ws + off); off += NF2;
    ushort* wlb   = (ushort*)(ws + off); off += WSZ;
    ushort* wrb   = (ushort*)(ws + off); off += WSZ;
    unsigned* degu   = (unsigned*)(ws + off); off += (size_t)N_NODES * 4;
    unsigned* excl   = (unsigned*)(ws + off); off += (size_t)N_NODES * 4;
    unsigned* bsum   = (unsigned*)(ws + off); off += 128 * 4;
    unsigned* rowptr = (unsigned*)(ws + off); off += (size_t)(N_NODES + 1) * 4;
    unsigned* cursor = (unsigned*)(ws + off); off += (size_t)N_NODES * 4;
    unsigned* col    = (unsigned*)(ws + off); off += (size_t)N_EDGES * 4;
    unsigned* gs     = (unsigned*)(ws + off); off += (size_t)N_GRAPHS * 4;
    unsigned* ge     = (unsigned*)(ws + off); off += (size_t)N_GRAPHS * 4;

    hipMemsetAsync(degu, 0, (size_t)N_NODES * 4, stream);
    hipMemsetAsync(gs, 0xFF, (size_t)N_GRAPHS * 4, stream);
    hipMemsetAsync(ge, 0, (size_t)N_GRAPHS * 4, stream);

    init_kernel<<<(N_NODES * FEAT / 4 + 255) / 256, 256, 0, stream>>>(x, xb0);
    wconv_kernel<<<(N_LAYERS * FEAT * FEAT / 4 + 255) / 256, 256, 0, stream>>>(Wl, Wr, wlb, wrb);

    // CSR build
    const int NB_SCAN = (N_NODES + SCAN_B - 1) / SCAN_B;   // 98
    hist_kernel<<<(N_EDGES + 255) / 256, 256, 0, stream>>>(ei + N_EDGES, degu);
    scan_blocks<<<NB_SCAN, SCAN_B, 0, stream>>>(degu, excl, bsum);
    scan_tops<<<1, 1, 0, stream>>>(bsum, NB_SCAN);
    finalize_rowptr<<<(N_NODES + 256) / 256, 256, 0, stream>>>(excl, bsum, rowptr, cursor);
    scatter_kernel<<<(N_EDGES + 255) / 256, 256, 0, stream>>>(ei, cursor, col);

    bounds_kernel<<<(N_NODES + 255) / 256, 256, 0, stream>>>(batch, gs, ge);

    ushort* cur = xb0;
    ushort* nxt = xb1;
    for (int l = 0; l < N_LAYERS; ++l) {
        gemm_kernel<<<dim3((N_NODES + 63) / 64), 512, 0, stream>>>(
            rowptr, col, cur,
            wlb + (size_t)l * FEAT * FEAT, wrb + (size_t)l * FEAT * FEAT,
            bl + (size_t)l * FEAT, nxt);
        ushort* tmp = cur; cur = nxt; nxt = tmp;
    }

    smax_kernel<<<N_GRAPHS, 512, 0, stream>>>(cur, gs, ge, t, out);
}

// Round 15
// 760.452 us; speedup vs baseline: 1.1822x; 1.1822x over previous
//
#include <hip/hip_runtime.h>
#include <hip/hip_bf16.h>

#define N_NODES  100000
#define N_EDGES  300000
#define FEAT     256
#define N_GRAPHS 500
#define N_LAYERS 6
#define SCAN_B   1024

typedef __attribute__((ext_vector_type(8))) short v8s;   // 8 x bf16 bits (4 VGPRs)
typedef __attribute__((ext_vector_type(4))) float v4f;   // MFMA accumulator

__device__ __forceinline__ unsigned short f2bf(float f) {
    unsigned u = __float_as_uint(f);
    unsigned r = u + 0x7fffu + ((u >> 16) & 1u);   // RNE
    return (unsigned short)(r >> 16);
}
__device__ __forceinline__ float bf2f(unsigned short b) {
    return __uint_as_float(((unsigned)b) << 16);
}

__device__ __forceinline__ void gload16(const ushort* g, ushort* l) {
    __builtin_amdgcn_global_load_lds((const __attribute__((address_space(1))) void*)g,
                                     (__attribute__((address_space(3))) void*)l,
                                     16, 0, 0);
}

// ---- init: x (f32) -> xb (bf16) ----
__global__ __launch_bounds__(256) void init_kernel(const float* __restrict__ x,
                                                   ushort* __restrict__ xb) {
    int i = blockIdx.x * 256 + threadIdx.x;           // per 4 elements
    if ((size_t)i * 4 >= (size_t)N_NODES * FEAT) return;
    float4 v = ((const float4*)x)[i];
    ((ushort4*)xb)[i] = make_ushort4(f2bf(v.x), f2bf(v.y), f2bf(v.z), f2bf(v.w));
}

// ---- weights f32 -> bf16, all layers at once ----
__global__ __launch_bounds__(256) void wconv_kernel(const float* __restrict__ Wl,
                                                    const float* __restrict__ Wr,
                                                    ushort* __restrict__ wlb,
                                                    ushort* __restrict__ wrb) {
    int i = blockIdx.x * 256 + threadIdx.x;           // per 4 elements
    if ((size_t)i * 4 >= (size_t)N_LAYERS * FEAT * FEAT) return;
    float4 a = ((const float4*)Wl)[i];
    float4 b = ((const float4*)Wr)[i];
    ((ushort4*)wlb)[i] = make_ushort4(f2bf(a.x), f2bf(a.y), f2bf(a.z), f2bf(a.w));
    ((ushort4*)wrb)[i] = make_ushort4(f2bf(b.x), f2bf(b.y), f2bf(b.z), f2bf(b.w));
}

// ================= CSR construction (counting sort by dst) =================

__global__ __launch_bounds__(256) void hist_kernel(const int* __restrict__ dst,
                                                   unsigned* __restrict__ degu) {
    int e = blockIdx.x * 256 + threadIdx.x;
    if (e < N_EDGES) atomicAdd(&degu[dst[e]], 1u);
}

__global__ __launch_bounds__(SCAN_B) void scan_blocks(const unsigned* __restrict__ degu,
                                                      unsigned* __restrict__ excl,
                                                      unsigned* __restrict__ bsum) {
    __shared__ unsigned tmp[SCAN_B];
    int i = blockIdx.x * SCAN_B + threadIdx.x;
    unsigned v = (i < N_NODES) ? degu[i] : 0u;
    tmp[threadIdx.x] = v;
    __syncthreads();
    for (int off = 1; off < SCAN_B; off <<= 1) {
        unsigned add = (threadIdx.x >= off) ? tmp[threadIdx.x - off] : 0u;
        __syncthreads();
        tmp[threadIdx.x] += add;
        __syncthreads();
    }
    if (i < N_NODES) excl[i] = tmp[threadIdx.x] - v;
    if (threadIdx.x == SCAN_B - 1) bsum[blockIdx.x] = tmp[SCAN_B - 1];
}

__global__ void scan_tops(unsigned* __restrict__ bsum, int nb) {
    unsigned run = 0;
    for (int b = 0; b < nb; ++b) { unsigned t = bsum[b]; bsum[b] = run; run += t; }
}

__global__ __launch_bounds__(256) void finalize_rowptr(const unsigned* __restrict__ excl,
                                                       const unsigned* __restrict__ bsum,
                                                       unsigned* __restrict__ rowptr,
                                                       unsigned* __restrict__ cursor) {
    int i = blockIdx.x * 256 + threadIdx.x;
    if (i < N_NODES) {
        unsigned v = excl[i] + bsum[i / SCAN_B];
        rowptr[i] = v;
        cursor[i] = v;
    }
    if (i == N_NODES) rowptr[N_NODES] = N_EDGES;
}

__global__ __launch_bounds__(256) void scatter_kernel(const int* __restrict__ ei,
                                                      unsigned* __restrict__ cursor,
                                                      unsigned* __restrict__ col) {
    int e = blockIdx.x * 256 + threadIdx.x;
    if (e >= N_EDGES) return;
    int d = ei[N_EDGES + e];
    unsigned p = atomicAdd(&cursor[d], 1u);
    col[p] = (unsigned)ei[e];
}

// ---- per-graph [start,end) bounds from sorted batch: boundary detection ----
__global__ __launch_bounds__(256) void bounds_kernel(const int* __restrict__ batch,
                                                     unsigned* __restrict__ gs,
                                                     unsigned* __restrict__ ge) {
    int i = blockIdx.x * 256 + threadIdx.x;
    if (i >= N_NODES) return;
    int g = batch[i];
    int gp = (i == 0) ? -1 : batch[i - 1];
    if (g != gp) gs[g] = (unsigned)i;
    int gn = (i == N_NODES - 1) ? -1 : batch[i + 1];
    if (g != gn) ge[g] = (unsigned)(i + 1);
}

// ============================================================================
// Fused layer v6: mean-gather(64 nodes)->LDS (R13 masked-4wide), then
//   xbn = bf16( relu([mean|x] @ [Wl|Wr]^T + bl) + x )
// BM=64, BN=256, BK=32, 8 waves (1x8 col stripes), grid 1563.
// v6: B operand lives in REGISTERS (per-wave 32-row stripe, global loads from
// L2-hot weights, double-buffered one phase ahead). No Bs LDS, no B staging.
//   - mean phases (kt 0..7): barrier-free (Ms read-only after gather sync).
//   - x phases (kt 8..15): R13 wait-then-issue, STAGE_X only.
// LDS 40 KB (Ms 32 + Xs ring 8) -> 3 blocks/CU target; lb(512,6) caps VGPR 85.
// ============================================================================
#define CPAD  264    // epilogue row stride (256 + 8)

__global__ __launch_bounds__(512, 6) void gemm_kernel(
        const unsigned* __restrict__ rowptr,
        const unsigned* __restrict__ col,
        const ushort* __restrict__ xb,    // cur x (row-major bf16)
        const ushort* __restrict__ B0,    // Wl slice [256][256]
        const ushort* __restrict__ B1,    // Wr slice
        const float*  __restrict__ bias,  // bl slice [256]
        ushort* __restrict__ xbn) {       // next-layer x
    __shared__ ushort lds[20480];         // 40 KB
    ushort* Ms  = lds;                    // [64][512B] chunk-XOR swz   (32 KB)
    ushort* Xs0 = lds + 16384;            // [64 rows x 32k] 2r/128B    ( 4 KB)
    ushort* Xs1 = lds + 18432;            //                            ( 4 KB)
    ushort* Cs  = lds;                    // epilogue reuse [64][CPAD]  (33.8 KB)

    const int tid  = threadIdx.x;
    const int lane = tid & 63;
    const int wid  = tid >> 6;            // 0..7 (col stripe)
    const int row0 = blockIdx.x * 64;
    const int fr   = lane & 15;
    const int kq8  = (lane >> 4) << 3;    // 0,8,16,24 (elem offset in k-window)

    // ---- X staging addresses (tid<256: 16B chunk of the 4 KB tile) ----
    const int pX   = tid >> 3;
    const int w0X  = ((tid & 7) ^ (pX & 7)) << 4;
    int rX = row0 + 2 * pX + (w0X >> 6);
    rX = rX < N_NODES ? rX : N_NODES - 1;
    const int cbX  = w0X & 63;

    #define STAGE_X(bufPtr, kt) do {                                              \
        if (tid < 256) {                                                          \
            const int kb = ((kt) & 7) * 32;                                       \
            gload16(xb + (size_t)rX * FEAT + kb + (cbX >> 1), (bufPtr) + tid * 8);\
        }                                                                          \
    } while (0)

    // B fragment register load: wave's 32-row stripe, k-window kt
    #define LOADB(dst, Bsrc, kt) do {                                             \
        _Pragma("unroll")                                                         \
        for (int j = 0; j < 2; ++j)                                               \
            dst[j] = *(const v8s*)((Bsrc) +                                       \
                (size_t)(wid * 32 + j * 16 + fr) * FEAT + ((kt) & 7) * 32 + kq8); \
    } while (0)

    // ======================= gather: mean -> Ms (R13) =======================
    {
        const int h   = lane >> 5;        // half-wave: node parity
        const int l32 = lane & 31;        // 8 feats per lane
        #pragma unroll 2
        for (int p = 0; p < 4; ++p) {
            const int nl = wid * 8 + p * 2 + h;      // local row 0..63
            const int node = row0 + nl;
            unsigned s = 0, e = 0;
            if (node < N_NODES) { s = rowptr[node]; e = rowptr[node + 1]; }
            float a0=0.f,a1=0.f,a2=0.f,a3=0.f,a4=0.f,a5=0.f,a6=0.f,a7=0.f;
            #pragma unroll 1
            for (unsigned base = s; base < e; base += 32) {
                unsigned idx = base + (unsigned)l32;
                int cv = (idx < e) ? (int)col[idx] : 0;
                int n = (int)(e - base); n = n > 32 ? 32 : n;
                // masked 4-wide: ceil(n/4) latency rounds, lanes past n weight 0
                #pragma unroll 1
                for (int j = 0; j < n; j += 4) {
                    int nj = n - 1;
                    int l0 = (h << 5) + j;
                    int l1 = (h << 5) + (j + 1 < n ? j + 1 : nj);
                    int l2 = (h << 5) + (j + 2 < n ? j + 2 : nj);
                    int l3 = (h << 5) + (j + 3 < n ? j + 3 : nj);
                    float m1 = (j + 1 < n) ? 1.f : 0.f;
                    float m2 = (j + 2 < n) ? 1.f : 0.f;
                    float m3 = (j + 3 < n) ? 1.f : 0.f;
                    unsigned s0 = (unsigned)__shfl(cv, l0);
                    unsigned s1 = (unsigned)__shfl(cv, l1);
                    unsigned s2 = (unsigned)__shfl(cv, l2);
                    unsigned s3 = (unsigned)__shfl(cv, l3);
                    v8s v0 = *(const v8s*)(xb + (size_t)s0 * FEAT + l32 * 8);
                    v8s v1 = *(const v8s*)(xb + (size_t)s1 * FEAT + l32 * 8);
                    v8s v2 = *(const v8s*)(xb + (size_t)s2 * FEAT + l32 * 8);
                    v8s v3 = *(const v8s*)(xb + (size_t)s3 * FEAT + l32 * 8);
                    a0 += bf2f((ushort)v0[0]) + m1*bf2f((ushort)v1[0]) + m2*bf2f((ushort)v2[0]) + m3*bf2f((ushort)v3[0]);
                    a1 += bf2f((ushort)v0[1]) + m1*bf2f((ushort)v1[1]) + m2*bf2f((ushort)v2[1]) + m3*bf2f((ushort)v3[1]);
                    a2 += bf2f((ushort)v0[2]) + m1*bf2f((ushort)v1[2]) + m2*bf2f((ushort)v2[2]) + m3*bf2f((ushort)v3[2]);
                    a3 += bf2f((ushort)v0[3]) + m1*bf2f((ushort)v1[3]) + m2*bf2f((ushort)v2[3]) + m3*bf2f((ushort)v3[3]);
                    a4 += bf2f((ushort)v0[4]) + m1*bf2f((ushort)v1[4]) + m2*bf2f((ushort)v2[4]) + m3*bf2f((ushort)v3[4]);
                    a5 += bf2f((ushort)v0[5]) + m1*bf2f((ushort)v1[5]) + m2*bf2f((ushort)v2[5]) + m3*bf2f((ushort)v3[5]);
                    a6 += bf2f((ushort)v0[6]) + m1*bf2f((ushort)v1[6]) + m2*bf2f((ushort)v2[6]) + m3*bf2f((ushort)v3[6]);
                    a7 += bf2f((ushort)v0[7]) + m1*bf2f((ushort)v1[7]) + m2*bf2f((ushort)v2[7]) + m3*bf2f((ushort)v3[7]);
                }
            }
            float r = 1.0f / fmaxf((float)(e - s), 1.0f);
            v8s o;
            o[0]=(short)f2bf(a0*r); o[1]=(short)f2bf(a1*r);
            o[2]=(short)f2bf(a2*r); o[3]=(short)f2bf(a3*r);
            o[4]=(short)f2bf(a4*r); o[5]=(short)f2bf(a5*r);
            o[6]=(short)f2bf(a6*r); o[7]=(short)f2bf(a7*r);
            *(v8s*)((char*)Ms + nl * 512 + ((l32 * 16) ^ ((nl & 7) << 4))) = o;
        }
    }
    __syncthreads();   // Ms visible to all waves

    // ======================= K-loop =======================
    v4f acc[4][2] = {};
    const int cbk = (lane >> 4) << 4;

    #define FRAG(basePtr, row) \
        (*(const v8s*)((const char*)(basePtr) + (((row) >> 1) * 128 + \
            ((((row) & 1) << 6) + cbk) ^ ((((row) >> 1) & 7) << 4))))

    #define AFRAG_M(kt, row) \
        (*(const v8s*)((const char*)Ms + (row) * 512 + \
            ((((kt) << 6) + cbk) ^ (((row) & 7) << 4))))

    #define MFMA8(bv) do {                                                        \
        _Pragma("unroll")                                                         \
        for (int i = 0; i < 4; ++i)                                               \
            _Pragma("unroll")                                                     \
            for (int j = 0; j < 2; ++j)                                           \
                acc[i][j] = __builtin_amdgcn_mfma_f32_16x16x32_bf16(a[i], bv[j], acc[i][j], 0, 0, 0); \
    } while (0)

    v8s pbA[2], pbB[2];
    LOADB(pbA, B0, 0);

    // ---- mean @ Wl phases (kt 0..7): barrier-free, B in registers ----
    #pragma unroll
    for (int kt = 0; kt < 8; ++kt) {
        if (kt == 5) STAGE_X(Xs0, 8);                 // early issue: lands during kt 5..7
        // prefetch B(kt+1) into the other parity buffer
        if (kt & 1) { if (kt < 7) LOADB(pbA, B0, kt + 1); else LOADB(pbA, B1, 8); }
        else        { LOADB(pbB, B0, kt + 1); }
        v8s a[4];
        #pragma unroll
        for (int i = 0; i < 4; ++i) a[i] = AFRAG_M(kt, i * 16 + fr);
        if (kt & 1) { MFMA8(pbB); } else { MFMA8(pbA); }
    }

    // ---- x @ Wr phases (kt 8..15): wait-then-issue, STAGE_X only ----
    #pragma unroll
    for (int kt = 8; kt < 16; ++kt) {
        asm volatile("s_waitcnt vmcnt(0)" ::: "memory");   // stage_X(kt)+pb(kt) landed
        __builtin_amdgcn_s_barrier();                      // all waves done with other Xs buf
        if (kt < 15) {
            STAGE_X((kt & 1) ? Xs0 : Xs1, kt + 1);
            if (kt & 1) LOADB(pbA, B1, kt + 1); else LOADB(pbB, B1, kt + 1);
        }
        v8s a[4];
        const ushort* xp = (kt & 1) ? Xs1 : Xs0;
        #pragma unroll
        for (int i = 0; i < 4; ++i) a[i] = FRAG(xp, i * 16 + fr);
        asm volatile("s_waitcnt lgkmcnt(0)" ::: "memory");
        __builtin_amdgcn_sched_barrier(0);
        __builtin_amdgcn_s_setprio(1);
        if (kt & 1) { MFMA8(pbB); } else { MFMA8(pbA); }
        __builtin_amdgcn_s_setprio(0);
    }

    // ================= epilogue (coalesced via LDS) =================
    __builtin_amdgcn_s_barrier();   // all waves past final Xs/Ms reads
    {
        const int orow = (lane >> 4) * 4;
        const int ocol = lane & 15;
        #pragma unroll
        for (int j = 0; j < 2; ++j) {
            int colg = wid * 32 + j * 16 + ocol;
            float bv = bias[colg];
            #pragma unroll
            for (int i = 0; i < 4; ++i) {
                int rl = i * 16 + orow;
                #pragma unroll
                for (int r = 0; r < 4; ++r)
                    Cs[(rl + r) * CPAD + colg] = f2bf(fmaxf(acc[i][j][r] + bv, 0.0f));
            }
        }
    }
    __syncthreads();                // ds_writes drained + visible
    {
        int rl  = tid >> 3;                  // 0..63
        int row = row0 + rl;
        #pragma unroll
        for (int it = 0; it < 4; ++it) {
            int c0 = (tid & 7) * 8 + it * 64;
            v8s y = *(const v8s*)(Cs + rl * CPAD + c0);
            if (row < N_NODES) {
                v8s xv = *(const v8s*)(xb + (size_t)row * FEAT + c0);
                v8s o;
                #pragma unroll
                for (int k = 0; k < 8; ++k)
                    o[k] = (short)f2bf(bf2f((ushort)y[k]) + bf2f((ushort)xv[k]));
                *(v8s*)(xbn + (size_t)row * FEAT + c0) = o;
            }
        }
    }
    #undef STAGE_X
    #undef LOADB
    #undef FRAG
    #undef AFRAG_M
    #undef MFMA8
}

// ============================================================================
// Parallel segment softmax (R10): 1 block (512 thr) per graph.
// ============================================================================
__global__ __launch_bounds__(512) void smax_kernel(const ushort* __restrict__ xb,
                                                   const unsigned* __restrict__ gs,
                                                   const unsigned* __restrict__ ge,
                                                   const float* __restrict__ t,
                                                   float* __restrict__ out) {
    __shared__ float sm[16 * 256];
    __shared__ float sd[16 * 256];
    __shared__ float sa[16 * 256];
    const int g   = blockIdx.x;
    const unsigned s = gs[g], e = ge[g];
    const float tv2 = t[0] * 1.44269504f;   // log2(e) * t
    const int tid = threadIdx.x;
    const int c   = tid >> 5;               // chunk 0..15
    const int f8  = (tid & 31) * 8;         // feature base

    float m[8], den[8], acc[8];
    #pragma unroll
    for (int k = 0; k < 8; ++k) { m[k] = -INFINITY; den[k] = 0.f; acc[k] = 0.f; }

    if (s < e) {
        for (unsigned n = s + c; n < e; n += 16) {
            v8s v = *(const v8s*)(xb + (size_t)n * FEAT + f8);
            #pragma unroll
            for (int k = 0; k < 8; ++k) {
                float xv = bf2f((ushort)v[k]);
                float s2 = xv * tv2;                 // t*x in log2 domain
                float mn = fmaxf(m[k], s2);
                float sc = exp2f(m[k] - mn);         // 0 on first iter
                float w  = exp2f(s2 - mn);
                den[k] = den[k] * sc + w;
                acc[k] = acc[k] * sc + w * xv;
                m[k] = mn;
            }
        }
    }
    #pragma unroll
    for (int k = 0; k < 8; ++k) {
        sm[c * 256 + f8 + k] = m[k];
        sd[c * 256 + f8 + k] = den[k];
        sa[c * 256 + f8 + k] = acc[k];
    }
    __syncthreads();
    if (tid < 256) {
        if (s < e) {
            const int f = tid;
            float M = -INFINITY;
            #pragma unroll
            for (int cc = 0; cc < 16; ++cc) M = fmaxf(M, sm[cc * 256 + f]);
            float D = 0.f, A = 0.f;
            #pragma unroll
            for (int cc = 0; cc < 16; ++cc) {
                float w = exp2f(sm[cc * 256 + f] - M);   // 0 for empty chunks
                D += sd[cc * 256 + f] * w;
                A += sa[cc * 256 + f] * w;
            }
            out[(size_t)g * FEAT + tid] = A / fmaxf(D, 1e-16f);
        } else {
            out[(size_t)g * FEAT + tid] = 0.f;   // empty segment -> 0 per reference
        }
    }
}

extern "C" void kernel_launch(void* const* d_in, const int* in_sizes, int n_in,
                              void* d_out, int out_size, void* d_ws, size_t ws_size,
                              hipStream_t stream) {
    const float* x     = (const float*)d_in[0];
    const int*   ei    = (const int*)d_in[1];    // [2, E]: row0=src, row1=dst
    const int*   batch = (const int*)d_in[2];
    const float* Wl    = (const float*)d_in[3];  // [L, F, F]
    const float* bl    = (const float*)d_in[4];  // [L, F]
    const float* Wr    = (const float*)d_in[5];  // [L, F, F]
    const float* t     = (const float*)d_in[6];  // [1]
    float* out = (float*)d_out;

    const size_t NF2 = (size_t)N_NODES * FEAT * 2;   // 51,200,000
    const size_t WSZ = (size_t)N_LAYERS * FEAT * FEAT * 2;

    char* ws = (char*)d_ws;
    size_t off = 0;
    ushort* xb0   = (ushort*)(ws + off); off += NF2;
    ushort* xb1   = (ushort*)(ws + off); off += NF2;
    ushort* wlb   = (ushort*)(ws + off); off += WSZ;
    ushort* wrb   = (ushort*)(ws + off); off += WSZ;
    unsigned* degu   = (unsigned*)(ws + off); off += (size_t)N_NODES * 4;
    unsigned* excl   = (unsigned*)(ws + off); off += (size_t)N_NODES * 4;
    unsigned* bsum   = (unsigned*)(ws + off); off += 128 * 4;
    unsigned* rowptr = (unsigned*)(ws + off); off += (size_t)(N_NODES + 1) * 4;
    unsigned* cursor = (unsigned*)(ws + off); off += (size_t)N_NODES * 4;
    unsigned* col    = (unsigned*)(ws + off); off += (size_t)N_EDGES * 4;
    unsigned* gs     = (unsigned*)(ws + off); off += (size_t)N_GRAPHS * 4;
    unsigned* ge     = (unsigned*)(ws + off); off += (size_t)N_GRAPHS * 4;

    hipMemsetAsync(degu, 0, (size_t)N_NODES * 4, stream);
    hipMemsetAsync(gs, 0xFF, (size_t)N_GRAPHS * 4, stream);
    hipMemsetAsync(ge, 0, (size_t)N_GRAPHS * 4, stream);

    init_kernel<<<(N_NODES * FEAT / 4 + 255) / 256, 256, 0, stream>>>(x, xb0);
    wconv_kernel<<<(N_LAYERS * FEAT * FEAT / 4 + 255) / 256, 256, 0, stream>>>(Wl, Wr, wlb, wrb);

    // CSR build
    const int NB_SCAN = (N_NODES + SCAN_B - 1) / SCAN_B;   // 98
    hist_kernel<<<(N_EDGES + 255) / 256, 256, 0, stream>>>(ei + N_EDGES, degu);
    scan_blocks<<<NB_SCAN, SCAN_B, 0, stream>>>(degu, excl, bsum);
    scan_tops<<<1, 1, 0, stream>>>(bsum, NB_SCAN);
    finalize_rowptr<<<(N_NODES + 256) / 256, 256, 0, stream>>>(excl, bsum, rowptr, cursor);
    scatter_kernel<<<(N_EDGES + 255) / 256, 256, 0, stream>>>(ei, cursor, col);

    bounds_kernel<<<(N_NODES + 255) / 256, 256, 0, stream>>>(batch, gs, ge);

    ushort* cur = xb0;
    ushort* nxt = xb1;
    for (int l = 0; l < N_LAYERS; ++l) {
        gemm_kernel<<<dim3((N_NODES + 63) / 64), 512, 0, stream>>>(
            rowptr, col, cur,
            wlb + (size_t)l * FEAT * FEAT, wrb + (size_t)l * FEAT * FEAT,
            bl + (size_t)l * FEAT, nxt);
        ushort* tmp = cur; cur = nxt; nxt = tmp;
    }

    smax_kernel<<<N_GRAPHS, 512, 0, stream>>>(cur, gs, ge, t, out);
}

// Round 16
// 666.667 us; speedup vs baseline: 1.3485x; 1.1407x over previous
//
#include <hip/hip_runtime.h>
#include <hip/hip_bf16.h>

#define N_NODES  100000
#define N_EDGES  300000
#define FEAT     256
#define N_GRAPHS 500
#define N_LAYERS 6
#define SCAN_B   1024

typedef __attribute__((ext_vector_type(8))) short v8s;   // 8 x bf16 bits (4 VGPRs)
typedef __attribute__((ext_vector_type(4))) float v4f;   // MFMA accumulator

__device__ __forceinline__ unsigned short f2bf(float f) {
    unsigned u = __float_as_uint(f);
    unsigned r = u + 0x7fffu + ((u >> 16) & 1u);   // RNE
    return (unsigned short)(r >> 16);
}
__device__ __forceinline__ float bf2f(unsigned short b) {
    return __uint_as_float(((unsigned)b) << 16);
}

__device__ __forceinline__ void gload16(const ushort* g, ushort* l) {
    __builtin_amdgcn_global_load_lds((const __attribute__((address_space(1))) void*)g,
                                     (__attribute__((address_space(3))) void*)l,
                                     16, 0, 0);
}

// ---- init: x (f32) -> xb (bf16) ----
__global__ __launch_bounds__(256) void init_kernel(const float* __restrict__ x,
                                                   ushort* __restrict__ xb) {
    int i = blockIdx.x * 256 + threadIdx.x;           // per 4 elements
    if ((size_t)i * 4 >= (size_t)N_NODES * FEAT) return;
    float4 v = ((const float4*)x)[i];
    ((ushort4*)xb)[i] = make_ushort4(f2bf(v.x), f2bf(v.y), f2bf(v.z), f2bf(v.w));
}

// ---- weights f32 -> bf16, all layers at once ----
__global__ __launch_bounds__(256) void wconv_kernel(const float* __restrict__ Wl,
                                                    const float* __restrict__ Wr,
                                                    ushort* __restrict__ wlb,
                                                    ushort* __restrict__ wrb) {
    int i = blockIdx.x * 256 + threadIdx.x;           // per 4 elements
    if ((size_t)i * 4 >= (size_t)N_LAYERS * FEAT * FEAT) return;
    float4 a = ((const float4*)Wl)[i];
    float4 b = ((const float4*)Wr)[i];
    ((ushort4*)wlb)[i] = make_ushort4(f2bf(a.x), f2bf(a.y), f2bf(a.z), f2bf(a.w));
    ((ushort4*)wrb)[i] = make_ushort4(f2bf(b.x), f2bf(b.y), f2bf(b.z), f2bf(b.w));
}

// ================= CSR construction (counting sort by dst) =================

__global__ __launch_bounds__(256) void hist_kernel(const int* __restrict__ dst,
                                                   unsigned* __restrict__ degu) {
    int e = blockIdx.x * 256 + threadIdx.x;
    if (e < N_EDGES) atomicAdd(&degu[dst[e]], 1u);
}

__global__ __launch_bounds__(SCAN_B) void scan_blocks(const unsigned* __restrict__ degu,
                                                      unsigned* __restrict__ excl,
                                                      unsigned* __restrict__ bsum) {
    __shared__ unsigned tmp[SCAN_B];
    int i = blockIdx.x * SCAN_B + threadIdx.x;
    unsigned v = (i < N_NODES) ? degu[i] : 0u;
    tmp[threadIdx.x] = v;
    __syncthreads();
    for (int off = 1; off < SCAN_B; off <<= 1) {
        unsigned add = (threadIdx.x >= off) ? tmp[threadIdx.x - off] : 0u;
        __syncthreads();
        tmp[threadIdx.x] += add;
        __syncthreads();
    }
    if (i < N_NODES) excl[i] = tmp[threadIdx.x] - v;
    if (threadIdx.x == SCAN_B - 1) bsum[blockIdx.x] = tmp[SCAN_B - 1];
}

__global__ void scan_tops(unsigned* __restrict__ bsum, int nb) {
    unsigned run = 0;
    for (int b = 0; b < nb; ++b) { unsigned t = bsum[b]; bsum[b] = run; run += t; }
}

__global__ __launch_bounds__(256) void finalize_rowptr(const unsigned* __restrict__ excl,
                                                       const unsigned* __restrict__ bsum,
                                                       unsigned* __restrict__ rowptr,
                                                       unsigned* __restrict__ cursor) {
    int i = blockIdx.x * 256 + threadIdx.x;
    if (i < N_NODES) {
        unsigned v = excl[i] + bsum[i / SCAN_B];
        rowptr[i] = v;
        cursor[i] = v;
    }
    if (i == N_NODES) rowptr[N_NODES] = N_EDGES;
}

__global__ __launch_bounds__(256) void scatter_kernel(const int* __restrict__ ei,
                                                      unsigned* __restrict__ cursor,
                                                      unsigned* __restrict__ col) {
    int e = blockIdx.x * 256 + threadIdx.x;
    if (e >= N_EDGES) return;
    int d = ei[N_EDGES + e];
    unsigned p = atomicAdd(&cursor[d], 1u);
    col[p] = (unsigned)ei[e];
}

// ---- per-graph [start,end) bounds from sorted batch: boundary detection ----
__global__ __launch_bounds__(256) void bounds_kernel(const int* __restrict__ batch,
                                                     unsigned* __restrict__ gs,
                                                     unsigned* __restrict__ ge) {
    int i = blockIdx.x * 256 + threadIdx.x;
    if (i >= N_NODES) return;
    int g = batch[i];
    int gp = (i == 0) ? -1 : batch[i - 1];
    if (g != gp) gs[g] = (unsigned)i;
    int gn = (i == N_NODES - 1) ? -1 : batch[i + 1];
    if (g != gn) ge[g] = (unsigned)(i + 1);
}

// ============================================================================
// Fused layer v6b: mean-gather(64 nodes)->LDS (R13 masked-4wide), then
//   xbn = bf16( relu([mean|x] @ [Wl|Wr]^T + bl) + x )
// BM=64, BN=256, BK=32, 8 waves (1x8 col stripes), grid 1563.
// B operand in REGISTERS (per-wave 32-row stripe, L2-hot weights, double-
// buffered one phase ahead). No Bs LDS, no B staging.
//   - mean phases (kt 0..7): barrier-free (Ms read-only after gather sync).
//   - x phases (kt 8..15): R13 wait-then-issue, STAGE_X only.
// LDS 40 KB. v6b fix vs R15: __launch_bounds__(512,4) -> VGPR cap 128
// (R15's (512,6) cap=85 forced spills: VGPR 40, WRITE +65MB scratch).
// ============================================================================
#define CPAD  264    // epilogue row stride (256 + 8)

__global__ __launch_bounds__(512, 4) void gemm_kernel(
        const unsigned* __restrict__ rowptr,
        const unsigned* __restrict__ col,
        const ushort* __restrict__ xb,    // cur x (row-major bf16)
        const ushort* __restrict__ B0,    // Wl slice [256][256]
        const ushort* __restrict__ B1,    // Wr slice
        const float*  __restrict__ bias,  // bl slice [256]
        ushort* __restrict__ xbn) {       // next-layer x
    __shared__ ushort lds[20480];         // 40 KB
    ushort* Ms  = lds;                    // [64][512B] chunk-XOR swz   (32 KB)
    ushort* Xs0 = lds + 16384;            // [64 rows x 32k] 2r/128B    ( 4 KB)
    ushort* Xs1 = lds + 18432;            //                            ( 4 KB)
    ushort* Cs  = lds;                    // epilogue reuse [64][CPAD]  (33.8 KB)

    const int tid  = threadIdx.x;
    const int lane = tid & 63;
    const int wid  = tid >> 6;            // 0..7 (col stripe)
    const int row0 = blockIdx.x * 64;
    const int fr   = lane & 15;
    const int kq8  = (lane >> 4) << 3;    // 0,8,16,24 (elem offset in k-window)

    // ---- X staging addresses (tid<256: 16B chunk of the 4 KB tile) ----
    const int pX   = tid >> 3;
    const int w0X  = ((tid & 7) ^ (pX & 7)) << 4;
    int rX = row0 + 2 * pX + (w0X >> 6);
    rX = rX < N_NODES ? rX : N_NODES - 1;
    const int cbX  = w0X & 63;

    #define STAGE_X(bufPtr, kt) do {                                              \
        if (tid < 256) {                                                          \
            const int kb = ((kt) & 7) * 32;                                       \
            gload16(xb + (size_t)rX * FEAT + kb + (cbX >> 1), (bufPtr) + tid * 8);\
        }                                                                          \
    } while (0)

    // B fragment register load: wave's 32-row stripe, k-window kt
    #define LOADB(dst, Bsrc, kt) do {                                             \
        _Pragma("unroll")                                                         \
        for (int j = 0; j < 2; ++j)                                               \
            dst[j] = *(const v8s*)((Bsrc) +                                       \
                (size_t)(wid * 32 + j * 16 + fr) * FEAT + ((kt) & 7) * 32 + kq8); \
    } while (0)

    // ======================= gather: mean -> Ms (R13) =======================
    {
        const int h   = lane >> 5;        // half-wave: node parity
        const int l32 = lane & 31;        // 8 feats per lane
        #pragma unroll 2
        for (int p = 0; p < 4; ++p) {
            const int nl = wid * 8 + p * 2 + h;      // local row 0..63
            const int node = row0 + nl;
            unsigned s = 0, e = 0;
            if (node < N_NODES) { s = rowptr[node]; e = rowptr[node + 1]; }
            float a0=0.f,a1=0.f,a2=0.f,a3=0.f,a4=0.f,a5=0.f,a6=0.f,a7=0.f;
            #pragma unroll 1
            for (unsigned base = s; base < e; base += 32) {
                unsigned idx = base + (unsigned)l32;
                int cv = (idx < e) ? (int)col[idx] : 0;
                int n = (int)(e - base); n = n > 32 ? 32 : n;
                // masked 4-wide: ceil(n/4) latency rounds, lanes past n weight 0
                #pragma unroll 1
                for (int j = 0; j < n; j += 4) {
                    int nj = n - 1;
                    int l0 = (h << 5) + j;
                    int l1 = (h << 5) + (j + 1 < n ? j + 1 : nj);
                    int l2 = (h << 5) + (j + 2 < n ? j + 2 : nj);
                    int l3 = (h << 5) + (j + 3 < n ? j + 3 : nj);
                    float m1 = (j + 1 < n) ? 1.f : 0.f;
                    float m2 = (j + 2 < n) ? 1.f : 0.f;
                    float m3 = (j + 3 < n) ? 1.f : 0.f;
                    unsigned s0 = (unsigned)__shfl(cv, l0);
                    unsigned s1 = (unsigned)__shfl(cv, l1);
                    unsigned s2 = (unsigned)__shfl(cv, l2);
                    unsigned s3 = (unsigned)__shfl(cv, l3);
                    v8s v0 = *(const v8s*)(xb + (size_t)s0 * FEAT + l32 * 8);
                    v8s v1 = *(const v8s*)(xb + (size_t)s1 * FEAT + l32 * 8);
                    v8s v2 = *(const v8s*)(xb + (size_t)s2 * FEAT + l32 * 8);
                    v8s v3 = *(const v8s*)(xb + (size_t)s3 * FEAT + l32 * 8);
                    a0 += bf2f((ushort)v0[0]) + m1*bf2f((ushort)v1[0]) + m2*bf2f((ushort)v2[0]) + m3*bf2f((ushort)v3[0]);
                    a1 += bf2f((ushort)v0[1]) + m1*bf2f((ushort)v1[1]) + m2*bf2f((ushort)v2[1]) + m3*bf2f((ushort)v3[1]);
                    a2 += bf2f((ushort)v0[2]) + m1*bf2f((ushort)v1[2]) + m2*bf2f((ushort)v2[2]) + m3*bf2f((ushort)v3[2]);
                    a3 += bf2f((ushort)v0[3]) + m1*bf2f((ushort)v1[3]) + m2*bf2f((ushort)v2[3]) + m3*bf2f((ushort)v3[3]);
                    a4 += bf2f((ushort)v0[4]) + m1*bf2f((ushort)v1[4]) + m2*bf2f((ushort)v2[4]) + m3*bf2f((ushort)v3[4]);
                    a5 += bf2f((ushort)v0[5]) + m1*bf2f((ushort)v1[5]) + m2*bf2f((ushort)v2[5]) + m3*bf2f((ushort)v3[5]);
                    a6 += bf2f((ushort)v0[6]) + m1*bf2f((ushort)v1[6]) + m2*bf2f((ushort)v2[6]) + m3*bf2f((ushort)v3[6]);
                    a7 += bf2f((ushort)v0[7]) + m1*bf2f((ushort)v1[7]) + m2*bf2f((ushort)v2[7]) + m3*bf2f((ushort)v3[7]);
                }
            }
            float r = 1.0f / fmaxf((float)(e - s), 1.0f);
            v8s o;
            o[0]=(short)f2bf(a0*r); o[1]=(short)f2bf(a1*r);
            o[2]=(short)f2bf(a2*r); o[3]=(short)f2bf(a3*r);
            o[4]=(short)f2bf(a4*r); o[5]=(short)f2bf(a5*r);
            o[6]=(short)f2bf(a6*r); o[7]=(short)f2bf(a7*r);
            *(v8s*)((char*)Ms + nl * 512 + ((l32 * 16) ^ ((nl & 7) << 4))) = o;
        }
    }
    __syncthreads();   // Ms visible to all waves

    // ======================= K-loop =======================
    v4f acc[4][2] = {};
    const int cbk = (lane >> 4) << 4;

    #define FRAG(basePtr, row) \
        (*(const v8s*)((const char*)(basePtr) + (((row) >> 1) * 128 + \
            ((((row) & 1) << 6) + cbk) ^ ((((row) >> 1) & 7) << 4))))

    #define AFRAG_M(kt, row) \
        (*(const v8s*)((const char*)Ms + (row) * 512 + \
            ((((kt) << 6) + cbk) ^ (((row) & 7) << 4))))

    #define MFMA8(bv) do {                                                        \
        _Pragma("unroll")                                                         \
        for (int i = 0; i < 4; ++i)                                               \
            _Pragma("unroll")                                                     \
            for (int j = 0; j < 2; ++j)                                           \
                acc[i][j] = __builtin_amdgcn_mfma_f32_16x16x32_bf16(a[i], bv[j], acc[i][j], 0, 0, 0); \
    } while (0)

    v8s pbA[2], pbB[2];
    LOADB(pbA, B0, 0);

    // ---- mean @ Wl phases (kt 0..7): barrier-free, B in registers ----
    #pragma unroll
    for (int kt = 0; kt < 8; ++kt) {
        if (kt == 5) STAGE_X(Xs0, 8);                 // early issue: lands during kt 5..7
        // prefetch B(kt+1) into the other parity buffer
        if (kt & 1) { if (kt < 7) LOADB(pbA, B0, kt + 1); else LOADB(pbA, B1, 8); }
        else        { LOADB(pbB, B0, kt + 1); }
        v8s a[4];
        #pragma unroll
        for (int i = 0; i < 4; ++i) a[i] = AFRAG_M(kt, i * 16 + fr);
        if (kt & 1) { MFMA8(pbB); } else { MFMA8(pbA); }
    }

    // ---- x @ Wr phases (kt 8..15): wait-then-issue, STAGE_X only ----
    #pragma unroll
    for (int kt = 8; kt < 16; ++kt) {
        asm volatile("s_waitcnt vmcnt(0)" ::: "memory");   // stage_X(kt)+pb(kt) landed
        __builtin_amdgcn_s_barrier();                      // all waves done with other Xs buf
        if (kt < 15) {
            STAGE_X((kt & 1) ? Xs0 : Xs1, kt + 1);
            if (kt & 1) LOADB(pbA, B1, kt + 1); else LOADB(pbB, B1, kt + 1);
        }
        v8s a[4];
        const ushort* xp = (kt & 1) ? Xs1 : Xs0;
        #pragma unroll
        for (int i = 0; i < 4; ++i) a[i] = FRAG(xp, i * 16 + fr);
        asm volatile("s_waitcnt lgkmcnt(0)" ::: "memory");
        __builtin_amdgcn_sched_barrier(0);
        __builtin_amdgcn_s_setprio(1);
        if (kt & 1) { MFMA8(pbB); } else { MFMA8(pbA); }
        __builtin_amdgcn_s_setprio(0);
    }

    // ================= epilogue (coalesced via LDS) =================
    __builtin_amdgcn_s_barrier();   // all waves past final Xs/Ms reads
    {
        const int orow = (lane >> 4) * 4;
        const int ocol = lane & 15;
        #pragma unroll
        for (int j = 0; j < 2; ++j) {
            int colg = wid * 32 + j * 16 + ocol;
            float bv = bias[colg];
            #pragma unroll
            for (int i = 0; i < 4; ++i) {
                int rl = i * 16 + orow;
                #pragma unroll
                for (int r = 0; r < 4; ++r)
                    Cs[(rl + r) * CPAD + colg] = f2bf(fmaxf(acc[i][j][r] + bv, 0.0f));
            }
        }
    }
    __syncthreads();                // ds_writes drained + visible
    {
        int rl  = tid >> 3;                  // 0..63
        int row = row0 + rl;
        #pragma unroll
        for (int it = 0; it < 4; ++it) {
            int c0 = (tid & 7) * 8 + it * 64;
            v8s y = *(const v8s*)(Cs + rl * CPAD + c0);
            if (row < N_NODES) {
                v8s xv = *(const v8s*)(xb + (size_t)row * FEAT + c0);
                v8s o;
                #pragma unroll
                for (int k = 0; k < 8; ++k)
                    o[k] = (short)f2bf(bf2f((ushort)y[k]) + bf2f((ushort)xv[k]));
                *(v8s*)(xbn + (size_t)row * FEAT + c0) = o;
            }
        }
    }
    #undef STAGE_X
    #undef LOADB
    #undef FRAG
    #undef AFRAG_M
    #undef MFMA8
}

// ============================================================================
// Parallel segment softmax (R10): 1 block (512 thr) per graph.
// ============================================================================
__global__ __launch_bounds__(512) void smax_kernel(const ushort* __restrict__ xb,
                                                   const unsigned* __restrict__ gs,
                                                   const unsigned* __restrict__ ge,
                                                   const float* __restrict__ t,
                                                   float* __restrict__ out) {
    __shared__ float sm[16 * 256];
    __shared__ float sd[16 * 256];
    __shared__ float sa[16 * 256];
    const int g   = blockIdx.x;
    const unsigned s = gs[g], e = ge[g];
    const float tv2 = t[0] * 1.44269504f;   // log2(e) * t
    const int tid = threadIdx.x;
    const int c   = tid >> 5;               // chunk 0..15
    const int f8  = (tid & 31) * 8;         // feature base

    float m[8], den[8], acc[8];
    #pragma unroll
    for (int k = 0; k < 8; ++k) { m[k] = -INFINITY; den[k] = 0.f; acc[k] = 0.f; }

    if (s < e) {
        for (unsigned n = s + c; n < e; n += 16) {
            v8s v = *(const v8s*)(xb + (size_t)n * FEAT + f8);
            #pragma unroll
            for (int k = 0; k < 8; ++k) {
                float xv = bf2f((ushort)v[k]);
                float s2 = xv * tv2;                 // t*x in log2 domain
                float mn = fmaxf(m[k], s2);
                float sc = exp2f(m[k] - mn);         // 0 on first iter
                float w  = exp2f(s2 - mn);
                den[k] = den[k] * sc + w;
                acc[k] = acc[k] * sc + w * xv;
                m[k] = mn;
            }
        }
    }
    #pragma unroll
    for (int k = 0; k < 8; ++k) {
        sm[c * 256 + f8 + k] = m[k];
        sd[c * 256 + f8 + k] = den[k];
        sa[c * 256 + f8 + k] = acc[k];
    }
    __syncthreads();
    if (tid < 256) {
        if (s < e) {
            const int f = tid;
            float M = -INFINITY;
            #pragma unroll
            for (int cc = 0; cc < 16; ++cc) M = fmaxf(M, sm[cc * 256 + f]);
            float D = 0.f, A = 0.f;
            #pragma unroll
            for (int cc = 0; cc < 16; ++cc) {
                float w = exp2f(sm[cc * 256 + f] - M);   // 0 for empty chunks
                D += sd[cc * 256 + f] * w;
                A += sa[cc * 256 + f] * w;
            }
            out[(size_t)g * FEAT + tid] = A / fmaxf(D, 1e-16f);
        } else {
            out[(size_t)g * FEAT + tid] = 0.f;   // empty segment -> 0 per reference
        }
    }
}

extern "C" void kernel_launch(void* const* d_in, const int* in_sizes, int n_in,
                              void* d_out, int out_size, void* d_ws, size_t ws_size,
                              hipStream_t stream) {
    const float* x     = (const float*)d_in[0];
    const int*   ei    = (const int*)d_in[1];    // [2, E]: row0=src, row1=dst
    const int*   batch = (const int*)d_in[2];
    const float* Wl    = (const float*)d_in[3];  // [L, F, F]
    const float* bl    = (const float*)d_in[4];  // [L, F]
    const float* Wr    = (const float*)d_in[5];  // [L, F, F]
    const float* t     = (const float*)d_in[6];  // [1]
    float* out = (float*)d_out;

    const size_t NF2 = (size_t)N_NODES * FEAT * 2;   // 51,200,000
    const size_t WSZ = (size_t)N_LAYERS * FEAT * FEAT * 2;

    char* ws = (char*)d_ws;
    size_t off = 0;
    ushort* xb0   = (ushort*)(ws + off); off += NF2;
    ushort* xb1   = (ushort*)(ws + off); off += NF2;
    ushort* wlb   = (ushort*)(ws + off); off += WSZ;
    ushort* wrb   = (ushort*)(ws + off); off += WSZ;
    unsigned* degu   = (unsigned*)(ws + off); off += (size_t)N_NODES * 4;
    unsigned* excl   = (unsigned*)(ws + off); off += (size_t)N_NODES * 4;
    unsigned* bsum   = (unsigned*)(ws + off); off += 128 * 4;
    unsigned* rowptr = (unsigned*)(ws + off); off += (size_t)(N_NODES + 1) * 4;
    unsigned* cursor = (unsigned*)(ws + off); off += (size_t)N_NODES * 4;
    unsigned* col    = (unsigned*)(ws + off); off += (size_t)N_EDGES * 4;
    unsigned* gs     = (unsigned*)(ws + off); off += (size_t)N_GRAPHS * 4;
    unsigned* ge     = (unsigned*)(ws + off); off += (size_t)N_GRAPHS * 4;

    hipMemsetAsync(degu, 0, (size_t)N_NODES * 4, stream);
    hipMemsetAsync(gs, 0xFF, (size_t)N_GRAPHS * 4, stream);
    hipMemsetAsync(ge, 0, (size_t)N_GRAPHS * 4, stream);

    init_kernel<<<(N_NODES * FEAT / 4 + 255) / 256, 256, 0, stream>>>(x, xb0);
    wconv_kernel<<<(N_LAYERS * FEAT * FEAT / 4 + 255) / 256, 256, 0, stream>>>(Wl, Wr, wlb, wrb);

    // CSR build
    const int NB_SCAN = (N_NODES + SCAN_B - 1) / SCAN_B;   // 98
    hist_kernel<<<(N_EDGES + 255) / 256, 256, 0, stream>>>(ei + N_EDGES, degu);
    scan_blocks<<<NB_SCAN, SCAN_B, 0, stream>>>(degu, excl, bsum);
    scan_tops<<<1, 1, 0, stream>>>(bsum, NB_SCAN);
    finalize_rowptr<<<(N_NODES + 256) / 256, 256, 0, stream>>>(excl, bsum, rowptr, cursor);
    scatter_kernel<<<(N_EDGES + 255) / 256, 256, 0, stream>>>(ei, cursor, col);

    bounds_kernel<<<(N_NODES + 255) / 256, 256, 0, stream>>>(batch, gs, ge);

    ushort* cur = xb0;
    ushort* nxt = xb1;
    for (int l = 0; l < N_LAYERS; ++l) {
        gemm_kernel<<<dim3((N_NODES + 63) / 64), 512, 0, stream>>>(
            rowptr, col, cur,
            wlb + (size_t)l * FEAT * FEAT, wrb + (size_t)l * FEAT * FEAT,
            bl + (size_t)l * FEAT, nxt);
        ushort* tmp = cur; cur = nxt; nxt = tmp;
    }

    smax_kernel<<<N_GRAPHS, 512, 0, stream>>>(cur, gs, ge, t, out);
}

// Round 17
// 548.062 us; speedup vs baseline: 1.6403x; 1.2164x over previous
//
#include <hip/hip_runtime.h>
#include <hip/hip_bf16.h>

#define N_NODES  100000
#define N_EDGES  300000
#define FEAT     256
#define N_GRAPHS 500
#define N_LAYERS 6
#define SCAN_B   1024

typedef __attribute__((ext_vector_type(8))) short v8s;   // 8 x bf16 bits (4 VGPRs)
typedef __attribute__((ext_vector_type(4))) float v4f;   // MFMA accumulator

__device__ __forceinline__ unsigned short f2bf(float f) {
    unsigned u = __float_as_uint(f);
    unsigned r = u + 0x7fffu + ((u >> 16) & 1u);   // RNE
    return (unsigned short)(r >> 16);
}
__device__ __forceinline__ float bf2f(unsigned short b) {
    return __uint_as_float(((unsigned)b) << 16);
}

__device__ __forceinline__ void gload16(const ushort* g, ushort* l) {
    __builtin_amdgcn_global_load_lds((const __attribute__((address_space(1))) void*)g,
                                     (__attribute__((address_space(3))) void*)l,
                                     16, 0, 0);
}

// ---- init: x (f32) -> xb (bf16) ----
__global__ __launch_bounds__(256) void init_kernel(const float* __restrict__ x,
                                                   ushort* __restrict__ xb) {
    int i = blockIdx.x * 256 + threadIdx.x;           // per 4 elements
    if ((size_t)i * 4 >= (size_t)N_NODES * FEAT) return;
    float4 v = ((const float4*)x)[i];
    ((ushort4*)xb)[i] = make_ushort4(f2bf(v.x), f2bf(v.y), f2bf(v.z), f2bf(v.w));
}

// ---- weights f32 -> bf16, all layers at once ----
__global__ __launch_bounds__(256) void wconv_kernel(const float* __restrict__ Wl,
                                                    const float* __restrict__ Wr,
                                                    ushort* __restrict__ wlb,
                                                    ushort* __restrict__ wrb) {
    int i = blockIdx.x * 256 + threadIdx.x;           // per 4 elements
    if ((size_t)i * 4 >= (size_t)N_LAYERS * FEAT * FEAT) return;
    float4 a = ((const float4*)Wl)[i];
    float4 b = ((const float4*)Wr)[i];
    ((ushort4*)wlb)[i] = make_ushort4(f2bf(a.x), f2bf(a.y), f2bf(a.z), f2bf(a.w));
    ((ushort4*)wrb)[i] = make_ushort4(f2bf(b.x), f2bf(b.y), f2bf(b.z), f2bf(b.w));
}

// ================= CSR construction (counting sort by dst) =================

__global__ __launch_bounds__(256) void hist_kernel(const int* __restrict__ dst,
                                                   unsigned* __restrict__ degu) {
    int e = blockIdx.x * 256 + threadIdx.x;
    if (e < N_EDGES) atomicAdd(&degu[dst[e]], 1u);
}

__global__ __launch_bounds__(SCAN_B) void scan_blocks(const unsigned* __restrict__ degu,
                                                      unsigned* __restrict__ excl,
                                                      unsigned* __restrict__ bsum) {
    __shared__ unsigned tmp[SCAN_B];
    int i = blockIdx.x * SCAN_B + threadIdx.x;
    unsigned v = (i < N_NODES) ? degu[i] : 0u;
    tmp[threadIdx.x] = v;
    __syncthreads();
    for (int off = 1; off < SCAN_B; off <<= 1) {
        unsigned add = (threadIdx.x >= off) ? tmp[threadIdx.x - off] : 0u;
        __syncthreads();
        tmp[threadIdx.x] += add;
        __syncthreads();
    }
    if (i < N_NODES) excl[i] = tmp[threadIdx.x] - v;
    if (threadIdx.x == SCAN_B - 1) bsum[blockIdx.x] = tmp[SCAN_B - 1];
}

__global__ void scan_tops(unsigned* __restrict__ bsum, int nb) {
    unsigned run = 0;
    for (int b = 0; b < nb; ++b) { unsigned t = bsum[b]; bsum[b] = run; run += t; }
}

__global__ __launch_bounds__(256) void finalize_rowptr(const unsigned* __restrict__ excl,
                                                       const unsigned* __restrict__ bsum,
                                                       unsigned* __restrict__ rowptr,
                                                       unsigned* __restrict__ cursor) {
    int i = blockIdx.x * 256 + threadIdx.x;
    if (i < N_NODES) {
        unsigned v = excl[i] + bsum[i / SCAN_B];
        rowptr[i] = v;
        cursor[i] = v;
    }
    if (i == N_NODES) rowptr[N_NODES] = N_EDGES;
}

__global__ __launch_bounds__(256) void scatter_kernel(const int* __restrict__ ei,
                                                      unsigned* __restrict__ cursor,
                                                      unsigned* __restrict__ col) {
    int e = blockIdx.x * 256 + threadIdx.x;
    if (e >= N_EDGES) return;
    int d = ei[N_EDGES + e];
    unsigned p = atomicAdd(&cursor[d], 1u);
    col[p] = (unsigned)ei[e];
}

// ---- per-graph [start,end) bounds from sorted batch: boundary detection ----
__global__ __launch_bounds__(256) void bounds_kernel(const int* __restrict__ batch,
                                                     unsigned* __restrict__ gs,
                                                     unsigned* __restrict__ ge) {
    int i = blockIdx.x * 256 + threadIdx.x;
    if (i >= N_NODES) return;
    int g = batch[i];
    int gp = (i == 0) ? -1 : batch[i - 1];
    if (g != gp) gs[g] = (unsigned)i;
    int gn = (i == N_NODES - 1) ? -1 : batch[i + 1];
    if (g != gn) ge[g] = (unsigned)(i + 1);
}

// ============================================================================
// Fused layer (R13 structure — verified best at 79 us/dispatch):
// mean-gather(64 nodes)->LDS (masked 4-wide), then
//   xbn = bf16( relu([mean|x] @ [Wl|Wr]^T + bl) + x )
// BM=64, BN=256, BK=32, 8 waves (1x8 col stripes), grid 1563.
//  - gather: masked 4-wide batches -> ceil(deg/4) latency rounds per node.
//  - K-loop: wait-then-issue phases (vmcnt(0) at top drains the stage issued
//    a FULL PHASE earlier; ONE barrier/phase; setprio around MFMA).
//  - epilogue: coalesced LDS round-trip (R9).
// Neighborhood explored and rejected: gather/phase interleave (R14, spills),
// occupancy 6 w/EU (R15, spills), B-in-registers (R16, -20%).
// ============================================================================
#define CPAD  264    // epilogue row stride (256 + 8)

__global__ __launch_bounds__(512, 4) void gemm_kernel(
        const unsigned* __restrict__ rowptr,
        const unsigned* __restrict__ col,
        const ushort* __restrict__ xb,    // cur x (row-major bf16)
        const ushort* __restrict__ B0,    // Wl slice [256][256]
        const ushort* __restrict__ B1,    // Wr slice
        const float*  __restrict__ bias,  // bl slice [256]
        ushort* __restrict__ xbn) {       // next-layer x
    __shared__ ushort lds[36864];         // 72 KB
    ushort* Ms  = lds;                    // 16384 ushorts (32 KB)
    ushort* Bs0 = lds + 16384;
    ushort* Bs1 = lds + 24576;
    ushort* Xs0 = lds + 32768;
    ushort* Xs1 = lds + 34816;
    ushort* Cs  = lds;                    // epilogue reuse [64][CPAD]

    const int tid  = threadIdx.x;
    const int lane = tid & 63;
    const int wid  = tid >> 6;            // 0..7 (col stripe)
    const int row0 = blockIdx.x * 64;

    // ---- staging address precompute ----
    const int pB0  = tid >> 3;
    const int w0B0 = ((tid & 7) ^ (pB0 & 7)) << 4;
    const int rB0  = 2 * pB0 + (w0B0 >> 6);
    const int cbB0 = w0B0 & 63;
    const int c1   = tid + 512;
    const int pB1  = c1 >> 3;
    const int w0B1 = ((c1 & 7) ^ (pB1 & 7)) << 4;
    const int rB1  = 2 * pB1 + (w0B1 >> 6);
    const int cbB1 = w0B1 & 63;
    const int pX   = tid >> 3;
    const int w0X  = ((tid & 7) ^ (pX & 7)) << 4;
    int rX = row0 + 2 * pX + (w0X >> 6);
    rX = rX < N_NODES ? rX : N_NODES - 1;
    const int cbX  = w0X & 63;

    #define STAGE_B(bufPtr, kt) do {                                              \
        const ushort* Bsrc = ((kt) < 8) ? B0 : B1;                                \
        const int kb = ((kt) & 7) * 32;                                           \
        gload16(Bsrc + (size_t)rB0 * FEAT + kb + (cbB0 >> 1), (bufPtr) + tid * 8);\
        gload16(Bsrc + (size_t)rB1 * FEAT + kb + (cbB1 >> 1), (bufPtr) + (size_t)c1 * 8); \
    } while (0)

    #define STAGE_X(bufPtr, kt) do {                                              \
        if (tid < 256) {                                                          \
            const int kb = ((kt) & 7) * 32;                                       \
            gload16(xb + (size_t)rX * FEAT + kb + (cbX >> 1), (bufPtr) + tid * 8);\
        }                                                                          \
    } while (0)

    STAGE_B(Bs0, 0);   // lands during gather

    // ======================= gather: mean -> Ms =======================
    {
        const int h   = lane >> 5;        // half-wave: node parity
        const int l32 = lane & 31;        // 8 feats per lane
        #pragma unroll 2
        for (int p = 0; p < 4; ++p) {
            const int nl = wid * 8 + p * 2 + h;      // local row 0..63
            const int node = row0 + nl;
            unsigned s = 0, e = 0;
            if (node < N_NODES) { s = rowptr[node]; e = rowptr[node + 1]; }
            float a0=0.f,a1=0.f,a2=0.f,a3=0.f,a4=0.f,a5=0.f,a6=0.f,a7=0.f;
            #pragma unroll 1
            for (unsigned base = s; base < e; base += 32) {
                unsigned idx = base + (unsigned)l32;
                int cv = (idx < e) ? (int)col[idx] : 0;
                int n = (int)(e - base); n = n > 32 ? 32 : n;
                // masked 4-wide: ceil(n/4) latency rounds, lanes past n weight 0
                #pragma unroll 1
                for (int j = 0; j < n; j += 4) {
                    int nj = n - 1;
                    int l0 = (h << 5) + j;
                    int l1 = (h << 5) + (j + 1 < n ? j + 1 : nj);
                    int l2 = (h << 5) + (j + 2 < n ? j + 2 : nj);
                    int l3 = (h << 5) + (j + 3 < n ? j + 3 : nj);
                    float m1 = (j + 1 < n) ? 1.f : 0.f;
                    float m2 = (j + 2 < n) ? 1.f : 0.f;
                    float m3 = (j + 3 < n) ? 1.f : 0.f;
                    unsigned s0 = (unsigned)__shfl(cv, l0);
                    unsigned s1 = (unsigned)__shfl(cv, l1);
                    unsigned s2 = (unsigned)__shfl(cv, l2);
                    unsigned s3 = (unsigned)__shfl(cv, l3);
                    v8s v0 = *(const v8s*)(xb + (size_t)s0 * FEAT + l32 * 8);
                    v8s v1 = *(const v8s*)(xb + (size_t)s1 * FEAT + l32 * 8);
                    v8s v2 = *(const v8s*)(xb + (size_t)s2 * FEAT + l32 * 8);
                    v8s v3 = *(const v8s*)(xb + (size_t)s3 * FEAT + l32 * 8);
                    a0 += bf2f((ushort)v0[0]) + m1*bf2f((ushort)v1[0]) + m2*bf2f((ushort)v2[0]) + m3*bf2f((ushort)v3[0]);
                    a1 += bf2f((ushort)v0[1]) + m1*bf2f((ushort)v1[1]) + m2*bf2f((ushort)v2[1]) + m3*bf2f((ushort)v3[1]);
                    a2 += bf2f((ushort)v0[2]) + m1*bf2f((ushort)v1[2]) + m2*bf2f((ushort)v2[2]) + m3*bf2f((ushort)v3[2]);
                    a3 += bf2f((ushort)v0[3]) + m1*bf2f((ushort)v1[3]) + m2*bf2f((ushort)v2[3]) + m3*bf2f((ushort)v3[3]);
                    a4 += bf2f((ushort)v0[4]) + m1*bf2f((ushort)v1[4]) + m2*bf2f((ushort)v2[4]) + m3*bf2f((ushort)v3[4]);
                    a5 += bf2f((ushort)v0[5]) + m1*bf2f((ushort)v1[5]) + m2*bf2f((ushort)v2[5]) + m3*bf2f((ushort)v3[5]);
                    a6 += bf2f((ushort)v0[6]) + m1*bf2f((ushort)v1[6]) + m2*bf2f((ushort)v2[6]) + m3*bf2f((ushort)v3[6]);
                    a7 += bf2f((ushort)v0[7]) + m1*bf2f((ushort)v1[7]) + m2*bf2f((ushort)v2[7]) + m3*bf2f((ushort)v3[7]);
                }
            }
            float r = 1.0f / fmaxf((float)(e - s), 1.0f);
            v8s o;
            o[0]=(short)f2bf(a0*r); o[1]=(short)f2bf(a1*r);
            o[2]=(short)f2bf(a2*r); o[3]=(short)f2bf(a3*r);
            o[4]=(short)f2bf(a4*r); o[5]=(short)f2bf(a5*r);
            o[6]=(short)f2bf(a6*r); o[7]=(short)f2bf(a7*r);
            *(v8s*)((char*)Ms + nl * 512 + ((l32 * 16) ^ ((nl & 7) << 4))) = o;
        }
    }
    __syncthreads();   // Ms ready; B(0) drained (full vmcnt drain)

    // ======================= K-loop (wait-then-issue) =======================
    v4f acc[4][2] = {};
    const int fr  = lane & 15;
    const int cbk = (lane >> 4) << 4;     // frag byte col within 64B k-window

    #define FRAG(basePtr, row) \
        (*(const v8s*)((const char*)(basePtr) + (((row) >> 1) * 128 + \
            ((((row) & 1) << 6) + cbk) ^ ((((row) >> 1) & 7) << 4))))

    #define AFRAG_M(kt, row) \
        (*(const v8s*)((const char*)Ms + (row) * 512 + \
            ((((kt) << 6) + cbk) ^ (((row) & 7) << 4))))

    #pragma unroll
    for (int kt = 0; kt < 16; ++kt) {
        if (kt > 0) {
            // stage(kt) was issued a full phase ago -> residual wait ~0
            asm volatile("s_waitcnt vmcnt(0)" ::: "memory");
            __builtin_amdgcn_s_barrier();      // all waves: stage(kt) landed, phase kt-1 reads done
        }
        if (kt < 15) {
            STAGE_B((kt & 1) ? Bs0 : Bs1, kt + 1);    // into the buffer last read at kt-1
            if (kt == 6) STAGE_X(Xs0, 8);             // extra phase of latency cover
            if (kt >= 8) STAGE_X((kt & 1) ? Xs0 : Xs1, kt + 1);
        }
        v8s a[4], b[2];
        if (kt < 8) {
            #pragma unroll
            for (int i = 0; i < 4; ++i) a[i] = AFRAG_M(kt, i * 16 + fr);
        } else {
            const ushort* xp = (kt & 1) ? Xs1 : Xs0;
            #pragma unroll
            for (int i = 0; i < 4; ++i) a[i] = FRAG(xp, i * 16 + fr);
        }
        {
            const ushort* bp = (kt & 1) ? Bs1 : Bs0;
            #pragma unroll
            for (int j = 0; j < 2; ++j) b[j] = FRAG(bp, wid * 32 + j * 16 + fr);
        }
        asm volatile("s_waitcnt lgkmcnt(0)" ::: "memory");
        __builtin_amdgcn_sched_barrier(0);
        __builtin_amdgcn_s_setprio(1);
        #pragma unroll
        for (int i = 0; i < 4; ++i)
            #pragma unroll
            for (int j = 0; j < 2; ++j)
                acc[i][j] = __builtin_amdgcn_mfma_f32_16x16x32_bf16(a[i], b[j], acc[i][j], 0, 0, 0);
        __builtin_amdgcn_s_setprio(0);
    }
    #undef AFRAG_M

    // ================= epilogue (R9 coalesced) =================
    __builtin_amdgcn_s_barrier();   // all waves past phase-15 reads (Cs overlaps Ms + 1KB Bs0 only)
    {
        const int orow = (lane >> 4) * 4;
        const int ocol = lane & 15;
        #pragma unroll
        for (int j = 0; j < 2; ++j) {
            int colg = wid * 32 + j * 16 + ocol;
            float bv = bias[colg];
            #pragma unroll
            for (int i = 0; i < 4; ++i) {
                int rl = i * 16 + orow;
                #pragma unroll
                for (int r = 0; r < 4; ++r)
                    Cs[(rl + r) * CPAD + colg] = f2bf(fmaxf(acc[i][j][r] + bv, 0.0f));
            }
        }
    }
    __syncthreads();                // ds_writes drained + visible to all waves
    {
        int rl  = tid >> 3;                  // 0..63
        int row = row0 + rl;
        #pragma unroll
        for (int it = 0; it < 4; ++it) {
            int c0 = (tid & 7) * 8 + it * 64;
            v8s y = *(const v8s*)(Cs + rl * CPAD + c0);
            if (row < N_NODES) {
                v8s xv = *(const v8s*)(xb + (size_t)row * FEAT + c0);
                v8s o;
                #pragma unroll
                for (int k = 0; k < 8; ++k)
                    o[k] = (short)f2bf(bf2f((ushort)y[k]) + bf2f((ushort)xv[k]));
                *(v8s*)(xbn + (size_t)row * FEAT + c0) = o;
            }
        }
    }
    #undef STAGE_B
    #undef STAGE_X
    #undef FRAG
}

// ============================================================================
// Parallel segment softmax (R10): 1 block (512 thr) per graph.
// ============================================================================
__global__ __launch_bounds__(512) void smax_kernel(const ushort* __restrict__ xb,
                                                   const unsigned* __restrict__ gs,
                                                   const unsigned* __restrict__ ge,
                                                   const float* __restrict__ t,
                                                   float* __restrict__ out) {
    __shared__ float sm[16 * 256];
    __shared__ float sd[16 * 256];
    __shared__ float sa[16 * 256];
    const int g   = blockIdx.x;
    const unsigned s = gs[g], e = ge[g];
    const float tv2 = t[0] * 1.44269504f;   // log2(e) * t
    const int tid = threadIdx.x;
    const int c   = tid >> 5;               // chunk 0..15
    const int f8  = (tid & 31) * 8;         // feature base

    float m[8], den[8], acc[8];
    #pragma unroll
    for (int k = 0; k < 8; ++k) { m[k] = -INFINITY; den[k] = 0.f; acc[k] = 0.f; }

    if (s < e) {
        for (unsigned n = s + c; n < e; n += 16) {
            v8s v = *(const v8s*)(xb + (size_t)n * FEAT + f8);
            #pragma unroll
            for (int k = 0; k < 8; ++k) {
                float xv = bf2f((ushort)v[k]);
                float s2 = xv * tv2;                 // t*x in log2 domain
                float mn = fmaxf(m[k], s2);
                float sc = exp2f(m[k] - mn);         // 0 on first iter
                float w  = exp2f(s2 - mn);
                den[k] = den[k] * sc + w;
                acc[k] = acc[k] * sc + w * xv;
                m[k] = mn;
            }
        }
    }
    #pragma unroll
    for (int k = 0; k < 8; ++k) {
        sm[c * 256 + f8 + k] = m[k];
        sd[c * 256 + f8 + k] = den[k];
        sa[c * 256 + f8 + k] = acc[k];
    }
    __syncthreads();
    if (tid < 256) {
        if (s < e) {
            const int f = tid;
            float M = -INFINITY;
            #pragma unroll
            for (int cc = 0; cc < 16; ++cc) M = fmaxf(M, sm[cc * 256 + f]);
            float D = 0.f, A = 0.f;
            #pragma unroll
            for (int cc = 0; cc < 16; ++cc) {
                float w = exp2f(sm[cc * 256 + f] - M);   // 0 for empty chunks
                D += sd[cc * 256 + f] * w;
                A += sa[cc * 256 + f] * w;
            }
            out[(size_t)g * FEAT + tid] = A / fmaxf(D, 1e-16f);
        } else {
            out[(size_t)g * FEAT + tid] = 0.f;   // empty segment -> 0 per reference
        }
    }
}

extern "C" void kernel_launch(void* const* d_in, const int* in_sizes, int n_in,
                              void* d_out, int out_size, void* d_ws, size_t ws_size,
                              hipStream_t stream) {
    const float* x     = (const float*)d_in[0];
    const int*   ei    = (const int*)d_in[1];    // [2, E]: row0=src, row1=dst
    const int*   batch = (const int*)d_in[2];
    const float* Wl    = (const float*)d_in[3];  // [L, F, F]
    const float* bl    = (const float*)d_in[4];  // [L, F]
    const float* Wr    = (const float*)d_in[5];  // [L, F, F]
    const float* t     = (const float*)d_in[6];  // [1]
    float* out = (float*)d_out;

    const size_t NF2 = (size_t)N_NODES * FEAT * 2;   // 51,200,000
    const size_t WSZ = (size_t)N_LAYERS * FEAT * FEAT * 2;

    char* ws = (char*)d_ws;
    size_t off = 0;
    ushort* xb0   = (ushort*)(ws + off); off += NF2;
    ushort* xb1   = (ushort*)(ws + off); off += NF2;
    ushort* wlb   = (ushort*)(ws + off); off += WSZ;
    ushort* wrb   = (ushort*)(ws + off); off += WSZ;
    unsigned* degu   = (unsigned*)(ws + off); off += (size_t)N_NODES * 4;
    unsigned* excl   = (unsigned*)(ws + off); off += (size_t)N_NODES * 4;
    unsigned* bsum   = (unsigned*)(ws + off); off += 128 * 4;
    unsigned* rowptr = (unsigned*)(ws + off); off += (size_t)(N_NODES + 1) * 4;
    unsigned* cursor = (unsigned*)(ws + off); off += (size_t)N_NODES * 4;
    unsigned* col    = (unsigned*)(ws + off); off += (size_t)N_EDGES * 4;
    unsigned* gs     = (unsigned*)(ws + off); off += (size_t)N_GRAPHS * 4;
    unsigned* ge     = (unsigned*)(ws + off); off += (size_t)N_GRAPHS * 4;

    hipMemsetAsync(degu, 0, (size_t)N_NODES * 4, stream);
    hipMemsetAsync(gs, 0xFF, (size_t)N_GRAPHS * 4, stream);
    hipMemsetAsync(ge, 0, (size_t)N_GRAPHS * 4, stream);

    init_kernel<<<(N_NODES * FEAT / 4 + 255) / 256, 256, 0, stream>>>(x, xb0);
    wconv_kernel<<<(N_LAYERS * FEAT * FEAT / 4 + 255) / 256, 256, 0, stream>>>(Wl, Wr, wlb, wrb);

    // CSR build
    const int NB_SCAN = (N_NODES + SCAN_B - 1) / SCAN_B;   // 98
    hist_kernel<<<(N_EDGES + 255) / 256, 256, 0, stream>>>(ei + N_EDGES, degu);
    scan_blocks<<<NB_SCAN, SCAN_B, 0, stream>>>(degu, excl, bsum);
    scan_tops<<<1, 1, 0, stream>>>(bsum, NB_SCAN);
    finalize_rowptr<<<(N_NODES + 256) / 256, 256, 0, stream>>>(excl, bsum, rowptr, cursor);
    scatter_kernel<<<(N_EDGES + 255) / 256, 256, 0, stream>>>(ei, cursor, col);

    bounds_kernel<<<(N_NODES + 255) / 256, 256, 0, stream>>>(batch, gs, ge);

    ushort* cur = xb0;
    ushort* nxt = xb1;
    for (int l = 0; l < N_LAYERS; ++l) {
        gemm_kernel<<<dim3((N_NODES + 63) / 64), 512, 0, stream>>>(
            rowptr, col, cur,
            wlb + (size_t)l * FEAT * FEAT, wrb + (size_t)l * FEAT * FEAT,
            bl + (size_t)l * FEAT, nxt);
        ushort* tmp = cur; cur = nxt; nxt = tmp;
    }

    smax_kernel<<<N_GRAPHS, 512, 0, stream>>>(cur, gs, ge, t, out);
}